// Round 9
// baseline (650.326 us; speedup 1.0000x reference)
//
#include <hip/hip_runtime.h>
#include <hip/hip_bf16.h>

// ---------------------------------------------------------------------------
// 6-layer transformer forward, MI355X. f16 MFMA compute, f32 stats.
// Round 9: flash-v2 — no K/Q LDS staging (L2-direct fragments), no barriers,
//          8KB LDS, setprio on MFMA clusters. Setup kernels fused; head
//          fused via last-block ticket.
// ---------------------------------------------------------------------------

typedef _Float16 f16_t;
typedef _Float16 f16x8 __attribute__((ext_vector_type(8)));
typedef _Float16 f16x4 __attribute__((ext_vector_type(4)));
typedef _Float16 f16x2 __attribute__((ext_vector_type(2)));
typedef float    f32x4 __attribute__((ext_vector_type(4)));

#define LSTR 3145728LL  // per-layer transposed-weight stride (f16 elems)

__device__ __forceinline__ void gl_lds16(const f16_t* g, f16_t* l) {
    __builtin_amdgcn_global_load_lds(
        (const __attribute__((address_space(1))) unsigned int*)g,
        (__attribute__((address_space(3))) unsigned int*)l, 16, 0, 0);
}

// ---------------- pipelined batched GEMM: C = A[M,K] * (Bt[N,K])^T + bias ---
// A, Bt f16 row-major. blockIdx.z -> zh=z/zmod, zl=z%zmod; per-operand strides.
// Split-K via zmod=1: sAhi/sBhi = K-slice offset, sChi = C-slice stride.
// LDS: linear dest (global_load_lds), XOR-swizzled 16B k-chunk on BOTH the
// global source and the LDS read offset (rule #21). BK=64: swz=row&7;
// BK=32: swz=(row>>1)&3.
// VOUT=1 (QKV): cols>=1024 are V heads -> written transposed to vt
// ([b*8+h][64][512]) as f16x4 (4 consecutive t per fragment); qkv gets Q,K.
template<int BM, int BN, int BK, int WR, int WC, int OUTF16, int RELU, int VOUT>
__global__ void __launch_bounds__(256)
gemm_kernel(const f16_t* __restrict__ A, const f16_t* __restrict__ B,
            const float* __restrict__ bias, void* __restrict__ Cout,
            f16_t* __restrict__ vt,
            int M, int N, int K, int lda, int ldb, int ldc, int zmod,
            long long sAhi, long long sAlo, long long sBhi, long long sBlo,
            long long sChi, long long sClo)
{
    constexpr int WMT = BM / WR;
    constexpr int WNT = BN / WC;
    constexpr int MR  = WMT / 16;
    constexpr int NR  = WNT / 16;
    constexpr int KK  = BK / 32;        // 16x16x32 MFMA k-substeps per K-step
    constexpr int CPR = BK / 8;         // 16B chunks per LDS row
    constexpr int RS  = (BK == 32) ? 1 : 0;
    constexpr int IA  = BM * BK / 2048; // global_load_lds issues per thread
    constexpr int IB  = BN * BK / 2048;
    __shared__ __align__(16) f16_t As[2][BM][BK];
    __shared__ __align__(16) f16_t Bs[2][BN][BK];

    const int tid  = threadIdx.x;
    const int wid  = tid >> 6, lane = tid & 63;
    const int wr   = wid / WC, wc = wid % WC;
    const int z    = blockIdx.z;
    const int zh   = z / zmod, zl = z % zmod;
    const f16_t* Ab = A + (long long)zh * sAhi + (long long)zl * sAlo;
    const f16_t* Bb = B + (long long)zh * sBhi + (long long)zl * sBlo;
    const int m0 = blockIdx.x * BM;
    const int n0 = blockIdx.y * BN;

    f32x4 acc[MR][NR] = {};

    // ---- staging addresses: chunk c=i*256+tid; row=c/CPR, j=c%CPR, j^=swz
    const f16_t* srcA[IA]; const f16_t* srcB[IB];
#pragma unroll
    for (int i = 0; i < IA; ++i) {
        const int c = i * 256 + tid, row = c / CPR;
        const int kch = (c % CPR) ^ ((row >> RS) & (CPR - 1));
        srcA[i] = Ab + (long long)(m0 + row) * lda + kch * 8;
    }
#pragma unroll
    for (int i = 0; i < IB; ++i) {
        const int c = i * 256 + tid, row = c / CPR;
        const int kch = (c % CPR) ^ ((row >> RS) & (CPR - 1));
        srcB[i] = Bb + (long long)(n0 + row) * ldb + kch * 8;
    }
    auto stage = [&](int bf_, int t) {
        const int k0 = t * BK;
#pragma unroll
        for (int i = 0; i < IA; ++i)
            gl_lds16(srcA[i] + k0, &As[bf_][0][0] + (i * 256 + wid * 64) * 8);
#pragma unroll
        for (int i = 0; i < IB; ++i)
            gl_lds16(srcB[i] + k0, &Bs[bf_][0][0] + (i * 256 + wid * 64) * 8);
    };

    // ---- fragment read offsets (bytes), swizzled to match staged layout
    const int l15 = lane & 15;
    const int g   = lane >> 4;
    int aoff[MR][KK], boff[NR][KK];
#pragma unroll
    for (int m = 0; m < MR; ++m) {
        const int row = wr * WMT + m * 16 + l15;
        const int swz = ((row >> RS) & (CPR - 1)) << 4;
#pragma unroll
        for (int kk = 0; kk < KK; ++kk)
            aoff[m][kk] = ((row * BK + kk * 32 + g * 8) * 2) ^ swz;
    }
#pragma unroll
    for (int n = 0; n < NR; ++n) {
        const int row = wc * WNT + n * 16 + l15;
        const int swz = ((row >> RS) & (CPR - 1)) << 4;
#pragma unroll
        for (int kk = 0; kk < KK; ++kk)
            boff[n][kk] = ((row * BK + kk * 32 + g * 8) * 2) ^ swz;
    }

    const int NT = K / BK;
    stage(0, 0);
    __syncthreads();                    // drains vmcnt before barrier

    int buf = 0;
    for (int t = 0; t < NT; ++t) {
        if (t + 1 < NT) stage(buf ^ 1, t + 1);   // loads fly during MFMA
        const char* Al = (const char*)&As[buf][0][0];
        const char* Bl = (const char*)&Bs[buf][0][0];
        f16x8 af[MR][KK], bfr[NR][KK];
#pragma unroll
        for (int m = 0; m < MR; ++m)
#pragma unroll
            for (int kk = 0; kk < KK; ++kk) af[m][kk] = *(const f16x8*)(Al + aoff[m][kk]);
#pragma unroll
        for (int n = 0; n < NR; ++n)
#pragma unroll
            for (int kk = 0; kk < KK; ++kk) bfr[n][kk] = *(const f16x8*)(Bl + boff[n][kk]);
#pragma unroll
        for (int kk = 0; kk < KK; ++kk)
#pragma unroll
            for (int m = 0; m < MR; ++m)
#pragma unroll
                for (int n = 0; n < NR; ++n)
                    acc[m][n] = __builtin_amdgcn_mfma_f32_16x16x32_f16(af[m][kk], bfr[n][kk], acc[m][n], 0, 0, 0);
        __syncthreads();                // drains vmcnt+lgkmcnt, swap safe
        buf ^= 1;
    }

    const long long cOff = (long long)zh * sChi + (long long)zl * sClo;
    const int rbase = (lane >> 4) * 4;  // C/D: row=(lane>>4)*4+r, col=lane&15
#pragma unroll
    for (int m = 0; m < MR; ++m) {
        const int row = m0 + wr * WMT + m * 16 + rbase;
#pragma unroll
        for (int n = 0; n < NR; ++n) {
            const int col = n0 + wc * WNT + n * 16 + l15;
            const float bb = bias ? bias[col] : 0.0f;
            if (VOUT && col >= 1024) {  // V head -> transposed f16x4 store
                const int hh = (col - 1024) >> 6, dv = (col - 1024) & 63;
                const int bb_ = row >> 9, t0 = row & 511;
                f16x4 v4;
#pragma unroll
                for (int r = 0; r < 4; ++r) v4[r] = (f16_t)(acc[m][n][r] + bb);
                *(f16x4*)&vt[((long long)((bb_ * 8 + hh) * 64 + dv)) * 512 + t0] = v4;
            } else {
#pragma unroll
                for (int r = 0; r < 4; ++r) {
                    float v = acc[m][n][r] + bb;
                    if (RELU) v = fmaxf(v, 0.0f);
                    const long long idx = cOff + (long long)(row + r) * ldc + col;
                    if (OUTF16) ((f16_t*)Cout)[idx] = (f16_t)v;
                    else        ((float*)Cout)[idx] = v;
                }
            }
        }
    }
}

// ------- flash attention v2 per (b,h, 64-q tile): softmax(Q K^T) V -> ao ----
// No K/Q LDS staging: fragments read straight from global (L2-resident).
// Per-wave P buffer only (8KB LDS), zero barriers, waves fully independent.
__global__ void __launch_bounds__(256)
attn_flash_kernel(const f16_t* __restrict__ qkv, const f16_t* __restrict__ Vt,
                  f16_t* __restrict__ ao)
{
    __shared__ __align__(16) f16_t Ps[4][16 * 64]; // per-wave private
    const int tid = threadIdx.x, wid = tid >> 6, lane = tid & 63;
    const int l15 = lane & 15, g = lane >> 4;
    const int z = blockIdx.y, b = z >> 3, hh = z & 7;
    const int q0 = blockIdx.x * 64;
    const f16_t* Kbase = qkv + (long long)b * 512 * 1536 + 512 + hh * 64;
    const f16_t* Qbase = qkv + (long long)(b * 512 + q0) * 1536 + hh * 64;
    const f16_t* Vbase = Vt + (long long)z * 32768;

    // hoisted Q B-frags straight from global: q row = wid*16 + l15
    const int q = wid * 16 + l15;
    f16x8 qf[2];
#pragma unroll
    for (int k = 0; k < 2; ++k)
        qf[k] = *(const f16x8*)(Qbase + (long long)q * 1536 + k * 32 + g * 8);

    f32x4 ov[4] = {};                   // O rows q=g*4+r, cols dv=n*16+l15
    float m_run = -1e30f, l_run = 0.0f;
    f16_t* Pw = &Ps[wid][0];

    for (int ck = 0; ck < 8; ++ck) {
        const int kc0 = ck * 64;
        // V fragments (global, L2-resident)
        f16x8 vf[4][2];
#pragma unroll
        for (int n = 0; n < 4; ++n)
#pragma unroll
            for (int k = 0; k < 2; ++k)
                vf[n][k] = *(const f16x8*)(Vbase + (n * 16 + l15) * 512 + kc0 + k * 32 + g * 8);
        // K fragments (global): key row m*16+l15, 16B-contiguous dims
        f16x8 kf[4][2];
#pragma unroll
        for (int m = 0; m < 4; ++m) {
            const int key = kc0 + m * 16 + l15;
#pragma unroll
            for (int k = 0; k < 2; ++k)
                kf[m][k] = *(const f16x8*)(Kbase + (long long)key * 1536 + k * 32 + g * 8);
        }
        // S^T = K_chunk . Q^T : rows=keys, cols=q
        f32x4 s[4] = {};
        __builtin_amdgcn_s_setprio(1);
#pragma unroll
        for (int k = 0; k < 2; ++k)
#pragma unroll
            for (int m = 0; m < 4; ++m)
                s[m] = __builtin_amdgcn_mfma_f32_16x16x32_f16(kf[m][k], qf[k], s[m], 0, 0, 0);
        __builtin_amdgcn_s_setprio(0);
        // online softmax over keys for q = l15
        float cmax = -1e30f;
#pragma unroll
        for (int m = 0; m < 4; ++m)
#pragma unroll
            for (int r = 0; r < 4; ++r) cmax = fmaxf(cmax, s[m][r]);
        cmax = fmaxf(cmax, __shfl_xor(cmax, 16, 64));
        cmax = fmaxf(cmax, __shfl_xor(cmax, 32, 64));
        const float mnew = fmaxf(m_run, cmax);
        const float corr = __expf(m_run - mnew);
        float csum = 0.0f;
#pragma unroll
        for (int m = 0; m < 4; ++m) {
            f16x4 p4;
#pragma unroll
            for (int r = 0; r < 4; ++r) {
                const float pe = __expf(s[m][r] - mnew);
                csum += pe;
                p4[r] = (f16_t)pe;
            }
            *(f16x4*)(Pw + l15 * 64 + ((((m * 2 + (g >> 1)) ^ (l15 & 7))) << 3) + ((g & 1) << 2)) = p4;
        }
        csum += __shfl_xor(csum, 16, 64);
        csum += __shfl_xor(csum, 32, 64);
        l_run = l_run * corr + csum;
        m_run = mnew;
        float cr[4];
#pragma unroll
        for (int r = 0; r < 4; ++r) cr[r] = __shfl(corr, g * 4 + r, 64);
#pragma unroll
        for (int n = 0; n < 4; ++n)
#pragma unroll
            for (int r = 0; r < 4; ++r) ov[n][r] *= cr[r];
#pragma unroll
        for (int k = 0; k < 2; ++k) {
            const f16x8 pf = *(const f16x8*)(Pw + l15 * 64 + (((k * 4 + g) ^ (l15 & 7)) << 3));
            __builtin_amdgcn_s_setprio(1);
#pragma unroll
            for (int n = 0; n < 4; ++n)
                ov[n] = __builtin_amdgcn_mfma_f32_16x16x32_f16(pf, vf[n][k], ov[n], 0, 0, 0);
            __builtin_amdgcn_s_setprio(0);
        }
    }

    const float inv = 1.0f / l_run;
    float ir[4];
#pragma unroll
    for (int r = 0; r < 4; ++r) ir[r] = __shfl(inv, g * 4 + r, 64);
#pragma unroll
    for (int n = 0; n < 4; ++n)
#pragma unroll
        for (int r = 0; r < 4; ++r) {
            const long long row = b * 512 + q0 + wid * 16 + g * 4 + r;
            ao[row * 512 + hh * 64 + n * 16 + l15] = (f16_t)(ov[n][r] * ir[r]);
        }
}

// ---- fused setup: wconv (18432 blks) + embed (4096) + biascat (36) + cnt ---
__global__ void __launch_bounds__(256)
setup_kernel(const float* __restrict__ Wq, const float* __restrict__ Wk,
             const float* __restrict__ Wv, const float* __restrict__ Wo,
             const float* __restrict__ W1, const float* __restrict__ W2,
             f16_t* __restrict__ wT,
             const int* __restrict__ xt, const float* __restrict__ emb,
             f16_t* __restrict__ hb,
             const float* __restrict__ bq, const float* __restrict__ bk,
             const float* __restrict__ bv, float* __restrict__ qkvb,
             int* __restrict__ cnt)
{
    __shared__ float tile[32][33];
    const int blk = blockIdx.x;
    const int tid = threadIdx.x;
    if (blk < 18432) {                  // ---- weight convert+transpose
        const int layer = blk / 3072;
        const int r     = blk % 3072;
        const float* src; f16_t* dst; int R, C, tt;
        if (r < 1024) {
            const int mat = r >> 8; tt = r & 255; R = 512; C = 512;
            const float* s4 = (mat == 0) ? Wq : (mat == 1) ? Wk : (mat == 2) ? Wv : Wo;
            src = s4 + (long long)layer * 262144;
            dst = wT + (long long)layer * LSTR + (long long)mat * 262144;
        } else if (r < 2048) {
            tt = r - 1024; R = 512; C = 2048;
            src = W1 + (long long)layer * 1048576;
            dst = wT + (long long)layer * LSTR + 1048576;
        } else {
            tt = r - 2048; R = 2048; C = 512;
            src = W2 + (long long)layer * 1048576;
            dst = wT + (long long)layer * LSTR + 2097152;
        }
        const int tC = C >> 5;
        const int tr = tt / tC, tc = tt % tC;
        const int r0 = tr * 32, c0 = tc * 32;
        const int tx = tid & 31, ty = tid >> 5;
#pragma unroll
        for (int i = 0; i < 4; ++i)
            tile[ty + 8 * i][tx] = src[(long long)(r0 + ty + 8 * i) * C + c0 + tx];
        __syncthreads();
#pragma unroll
        for (int i = 0; i < 4; ++i)
            dst[(long long)(c0 + ty + 8 * i) * R + r0 + tx] = (f16_t)tile[tx][ty + 8 * i];
    } else if (blk < 18432 + 4096) {    // ---- embedding + sinusoidal PE
        const int row = blk - 18432;
        const int t   = row & 511;
        const int tok = xt[row];
#pragma unroll
        for (int s = 0; s < 2; ++s) {
            const int d = tid + s * 256;
            const int i = d >> 1;
            const float inv = expf((float)(2 * i) * (-9.210340371976184f / 512.0f));
            const float ang = (float)t * inv;
            const float pe  = (d & 1) ? cosf(ang) : sinf(ang);
            hb[(long long)row * 512 + d] = (f16_t)(emb[(long long)tok * 512 + d] + pe);
        }
    } else {                            // ---- bias concat + ticket reset
        const int i = (blk - 22528) * 256 + tid;
        if (i < 9216) {
            const int l = i / 1536, c = i % 1536;
            float v;
            if (c < 512)       v = bq[l * 512 + c];
            else if (c < 1024) v = bk[l * 512 + c - 512];
            else               v = bv[l * 512 + c - 1024];
            qkvb[i] = v;
        }
        if (blk == 22528 && tid == 0) *cnt = 0;
    }
}

// ---- hb = LN( sum_{s<ns} X[s] + bias + hb ); wave-per-row, no barriers -----
__global__ void __launch_bounds__(256)
add_ln_kernel(const f16_t* __restrict__ X, int ns, long long sstr,
              const float* __restrict__ bias,
              const float* __restrict__ g, const float* __restrict__ b,
              f16_t* __restrict__ Hf)
{
    const int wid = threadIdx.x >> 6, lane = threadIdx.x & 63;
    const long long row = (long long)blockIdx.x * 4 + wid;
    f16_t* h = Hf + row * 512;
    const int c0 = lane * 8;
    const f16x8 hv = *(const f16x8*)&h[c0];
    float v[8];
#pragma unroll
    for (int e = 0; e < 8; ++e) v[e] = (float)hv[e] + bias[c0 + e];
    for (int s = 0; s < ns; ++s) {
        const f16x8 xv = *(const f16x8*)&X[s * sstr + row * 512 + c0];
#pragma unroll
        for (int e = 0; e < 8; ++e) v[e] += (float)xv[e];
    }
    float sum = 0.0f, sq = 0.0f;
#pragma unroll
    for (int e = 0; e < 8; ++e) { sum += v[e]; sq += v[e] * v[e]; }
#pragma unroll
    for (int o = 1; o < 64; o <<= 1) {
        sum += __shfl_xor(sum, o, 64);
        sq  += __shfl_xor(sq,  o, 64);
    }
    const float mu = sum * (1.0f / 512.0f);
    float var = sq * (1.0f / 512.0f) - mu * mu;
    var = fmaxf(var, 0.0f);
    const float rs = rsqrtf(var + 1e-5f);
    f16x8 o8;
#pragma unroll
    for (int e = 0; e < 8; ++e)
        o8[e] = (f16_t)(g[c0 + e] * (v[e] - mu) * rs + b[c0 + e]);
    *(f16x8*)&h[c0] = o8;
}

// ---------------- classifier head: split reduce + last-block finish ---------
__global__ void __launch_bounds__(256)
head_kernel(const f16_t* __restrict__ hb, const float* __restrict__ Wout,
            const float* __restrict__ bout, float* __restrict__ partials,
            int* __restrict__ cnt, float* __restrict__ out)
{
    const int blk = blockIdx.x;         // 8 b * 64 chunks
    const int b = blk >> 6, chunk = blk & 63;
    const int tid = threadIdx.x;
    const f16_t* hp = hb + (long long)b * 262144 + (long long)chunk * 4096;
    float a0 = 0, a1 = 0, a2 = 0, a3 = 0, a4 = 0;
    for (int it = 0; it < 16; ++it) {
        const int idx = it * 256 + tid;
        const float hv = (float)hp[idx];
        const float* w = Wout + ((long long)chunk * 4096 + idx) * 5;
        a0 += hv * w[0]; a1 += hv * w[1]; a2 += hv * w[2]; a3 += hv * w[3]; a4 += hv * w[4];
    }
#pragma unroll
    for (int o = 32; o > 0; o >>= 1) {
        a0 += __shfl_down(a0, o, 64); a1 += __shfl_down(a1, o, 64); a2 += __shfl_down(a2, o, 64);
        a3 += __shfl_down(a3, o, 64); a4 += __shfl_down(a4, o, 64);
    }
    __shared__ float sm[4][5];
    __shared__ int ticket;
    const int lane = tid & 63, w = tid >> 6;
    if (lane == 0) { sm[w][0] = a0; sm[w][1] = a1; sm[w][2] = a2; sm[w][3] = a3; sm[w][4] = a4; }
    __syncthreads();
    if (tid < 5)
        partials[(long long)blk * 5 + tid] = sm[0][tid] + sm[1][tid] + sm[2][tid] + sm[3][tid];
    __threadfence();
    __syncthreads();
    if (tid == 0) ticket = atomicAdd(cnt, 1);
    __syncthreads();
    if (ticket == 511) {                // last block finishes the reduction
        __threadfence();
        if (tid < 40) {
            const int bb = tid / 5, c = tid % 5;
            float s = bout[c];
            const float* p = partials + (long long)bb * 64 * 5 + c;
            for (int ck = 0; ck < 64; ++ck) s += p[ck * 5];
            out[tid] = s;               // reference output dtype is float32
        }
    }
}

// ---------------------------------------------------------------------------
extern "C" void kernel_launch(void* const* d_in, const int* in_sizes, int n_in,
                              void* d_out, int out_size, void* d_ws, size_t ws_size,
                              hipStream_t stream)
{
    (void)in_sizes; (void)n_in; (void)out_size; (void)ws_size;
    const int*   x_tok = (const int*)  d_in[0];
    const float* emb   = (const float*)d_in[2];
    const float* Wq    = (const float*)d_in[3];
    const float* bq    = (const float*)d_in[4];
    const float* Wk    = (const float*)d_in[5];
    const float* bk    = (const float*)d_in[6];
    const float* Wv    = (const float*)d_in[7];
    const float* bv    = (const float*)d_in[8];
    const float* Wo    = (const float*)d_in[9];
    const float* bo    = (const float*)d_in[10];
    const float* gma   = (const float*)d_in[11];
    const float* bta   = (const float*)d_in[12];
    const float* W1    = (const float*)d_in[13];
    const float* b1    = (const float*)d_in[14];
    const float* W2    = (const float*)d_in[15];
    const float* b2    = (const float*)d_in[16];
    const float* Wout  = (const float*)d_in[17];
    const float* bout  = (const float*)d_in[18];

    char* ws = (char*)d_ws;
    size_t off = 0;
    auto take = [&](size_t bytes) { char* p = ws + off; off += (bytes + 255) & ~(size_t)255; return p; };
    f16_t* wT    = (f16_t*)take(18874368ULL * 2);  // transposed f16 weights
    f16_t* hb    = (f16_t*)take(2097152ULL * 2);   // residual stream (f16)
    f16_t* qkv   = (f16_t*)take(6291456ULL * 2);   // [4096][1536] (Q,K used)
    f16_t* Vt    = (f16_t*)take(2097152ULL * 2);   // [64][64][512]
    f16_t* ao    = (f16_t*)take(2097152ULL * 2);   // attn out [4096][512]
    f16_t* f1    = (f16_t*)take(8388608ULL * 2);   // ffn hidden [4096][2048]
    f16_t* t16   = (f16_t*)take(4ULL * 2097152ULL * 2); // split-K f16 partials
    float* qkvb  = (float*)take(9216ULL * 4);
    float* parts = (float*)take(2560ULL * 4);
    int*   cnt   = (int*)  take(256);

    setup_kernel<<<dim3(22564), 256, 0, stream>>>(Wq, Wk, Wv, Wo, W1, W2, wT,
                                                  x_tok, emb, hb, bq, bk, bv, qkvb, cnt);

    for (int l = 0; l < 6; ++l) {
        const f16_t* wl = wT + (long long)l * LSTR;
        // QKV: [4096,512]@[512,1536]; V heads written transposed to Vt
        gemm_kernel<64,128,64,2,2,1,0,1><<<dim3(64,12,1),256,0,stream>>>(hb, wl, qkvb + l*1536,
            qkv, Vt, 4096,1536,512, 512,512,1536, 1, 0,0,0,0,0,0);
        // flash attention v2: softmax(QK^T)V -> ao
        attn_flash_kernel<<<dim3(8,64),256,0,stream>>>(qkv, Vt, ao);
        // O proj: 64x128 split-K x2 (512 blocks) -> t16 slices
        gemm_kernel<64,128,64,2,2,1,0,0><<<dim3(64,4,2),256,0,stream>>>(ao, wl + 786432, nullptr,
            t16, nullptr, 4096,512,256, 512,512,512, 1, 256LL,0LL, 256LL,0LL, 2097152LL,0LL);
        add_ln_kernel<<<dim3(1024),256,0,stream>>>(t16, 2, 2097152LL, bo + l*512,
            gma + l*512, bta + l*512, hb);
        // FFN1 + relu -> f1 f16: 128x128/BK=32 (512 blocks, 2/CU uniform)
        gemm_kernel<128,128,32,2,2,1,1,0><<<dim3(32,16,1),256,0,stream>>>(hb, wl + 1048576, b1 + l*2048,
            f1, nullptr, 4096,2048,512, 512,512,2048, 1, 0,0,0,0,0,0);
        // FFN2: 128x128/BK=32 split-K x4 (512 blocks, 2/CU) -> t16 slices
        gemm_kernel<128,128,32,2,2,1,0,0><<<dim3(32,4,4),256,0,stream>>>(f1, wl + 2097152, nullptr,
            t16, nullptr, 4096,512,512, 2048,2048,512, 1, 512LL,0LL, 512LL,0LL, 2097152LL,0LL);
        add_ln_kernel<<<dim3(1024),256,0,stream>>>(t16, 4, 2097152LL, b2 + l*512,
            gma + l*512, bta + l*512, hb);
    }

    head_kernel<<<dim3(512),256,0,stream>>>(hb, Wout, bout, parts, cnt, (float*)d_out);
}

// Round 10
// 563.856 us; speedup vs baseline: 1.1534x; 1.1534x over previous
//
#include <hip/hip_runtime.h>
#include <hip/hip_bf16.h>

// ---------------------------------------------------------------------------
// 6-layer transformer forward, MI355X. f16 MFMA compute, f32 stats.
// Round 10: revert r9 regressions (flash back to K/Q-staged v1, head split,
//           no device fences); keep fused setup; add setprio to flash MFMA.
// ---------------------------------------------------------------------------

typedef _Float16 f16_t;
typedef _Float16 f16x8 __attribute__((ext_vector_type(8)));
typedef _Float16 f16x4 __attribute__((ext_vector_type(4)));
typedef _Float16 f16x2 __attribute__((ext_vector_type(2)));
typedef float    f32x4 __attribute__((ext_vector_type(4)));

#define LSTR 3145728LL  // per-layer transposed-weight stride (f16 elems)

__device__ __forceinline__ void gl_lds16(const f16_t* g, f16_t* l) {
    __builtin_amdgcn_global_load_lds(
        (const __attribute__((address_space(1))) unsigned int*)g,
        (__attribute__((address_space(3))) unsigned int*)l, 16, 0, 0);
}

// ---------------- pipelined batched GEMM: C = A[M,K] * (Bt[N,K])^T + bias ---
// A, Bt f16 row-major. blockIdx.z -> zh=z/zmod, zl=z%zmod; per-operand strides.
// Split-K via zmod=1: sAhi/sBhi = K-slice offset, sChi = C-slice stride.
// LDS: linear dest (global_load_lds), XOR-swizzled 16B k-chunk on BOTH the
// global source and the LDS read offset (rule #21). BK=64: swz=row&7;
// BK=32: swz=(row>>1)&3.
// VOUT=1 (QKV): cols>=1024 are V heads -> written transposed to vt
// ([b*8+h][64][512]) as f16x4 (4 consecutive t per fragment); qkv gets Q,K.
template<int BM, int BN, int BK, int WR, int WC, int OUTF16, int RELU, int VOUT>
__global__ void __launch_bounds__(256)
gemm_kernel(const f16_t* __restrict__ A, const f16_t* __restrict__ B,
            const float* __restrict__ bias, void* __restrict__ Cout,
            f16_t* __restrict__ vt,
            int M, int N, int K, int lda, int ldb, int ldc, int zmod,
            long long sAhi, long long sAlo, long long sBhi, long long sBlo,
            long long sChi, long long sClo)
{
    constexpr int WMT = BM / WR;
    constexpr int WNT = BN / WC;
    constexpr int MR  = WMT / 16;
    constexpr int NR  = WNT / 16;
    constexpr int KK  = BK / 32;        // 16x16x32 MFMA k-substeps per K-step
    constexpr int CPR = BK / 8;         // 16B chunks per LDS row
    constexpr int RS  = (BK == 32) ? 1 : 0;
    constexpr int IA  = BM * BK / 2048; // global_load_lds issues per thread
    constexpr int IB  = BN * BK / 2048;
    __shared__ __align__(16) f16_t As[2][BM][BK];
    __shared__ __align__(16) f16_t Bs[2][BN][BK];

    const int tid  = threadIdx.x;
    const int wid  = tid >> 6, lane = tid & 63;
    const int wr   = wid / WC, wc = wid % WC;
    const int z    = blockIdx.z;
    const int zh   = z / zmod, zl = z % zmod;
    const f16_t* Ab = A + (long long)zh * sAhi + (long long)zl * sAlo;
    const f16_t* Bb = B + (long long)zh * sBhi + (long long)zl * sBlo;
    const int m0 = blockIdx.x * BM;
    const int n0 = blockIdx.y * BN;

    f32x4 acc[MR][NR] = {};

    // ---- staging addresses: chunk c=i*256+tid; row=c/CPR, j=c%CPR, j^=swz
    const f16_t* srcA[IA]; const f16_t* srcB[IB];
#pragma unroll
    for (int i = 0; i < IA; ++i) {
        const int c = i * 256 + tid, row = c / CPR;
        const int kch = (c % CPR) ^ ((row >> RS) & (CPR - 1));
        srcA[i] = Ab + (long long)(m0 + row) * lda + kch * 8;
    }
#pragma unroll
    for (int i = 0; i < IB; ++i) {
        const int c = i * 256 + tid, row = c / CPR;
        const int kch = (c % CPR) ^ ((row >> RS) & (CPR - 1));
        srcB[i] = Bb + (long long)(n0 + row) * ldb + kch * 8;
    }
    auto stage = [&](int bf_, int t) {
        const int k0 = t * BK;
#pragma unroll
        for (int i = 0; i < IA; ++i)
            gl_lds16(srcA[i] + k0, &As[bf_][0][0] + (i * 256 + wid * 64) * 8);
#pragma unroll
        for (int i = 0; i < IB; ++i)
            gl_lds16(srcB[i] + k0, &Bs[bf_][0][0] + (i * 256 + wid * 64) * 8);
    };

    // ---- fragment read offsets (bytes), swizzled to match staged layout
    const int l15 = lane & 15;
    const int g   = lane >> 4;
    int aoff[MR][KK], boff[NR][KK];
#pragma unroll
    for (int m = 0; m < MR; ++m) {
        const int row = wr * WMT + m * 16 + l15;
        const int swz = ((row >> RS) & (CPR - 1)) << 4;
#pragma unroll
        for (int kk = 0; kk < KK; ++kk)
            aoff[m][kk] = ((row * BK + kk * 32 + g * 8) * 2) ^ swz;
    }
#pragma unroll
    for (int n = 0; n < NR; ++n) {
        const int row = wc * WNT + n * 16 + l15;
        const int swz = ((row >> RS) & (CPR - 1)) << 4;
#pragma unroll
        for (int kk = 0; kk < KK; ++kk)
            boff[n][kk] = ((row * BK + kk * 32 + g * 8) * 2) ^ swz;
    }

    const int NT = K / BK;
    stage(0, 0);
    __syncthreads();                    // drains vmcnt before barrier

    int buf = 0;
    for (int t = 0; t < NT; ++t) {
        if (t + 1 < NT) stage(buf ^ 1, t + 1);   // loads fly during MFMA
        const char* Al = (const char*)&As[buf][0][0];
        const char* Bl = (const char*)&Bs[buf][0][0];
        f16x8 af[MR][KK], bfr[NR][KK];
#pragma unroll
        for (int m = 0; m < MR; ++m)
#pragma unroll
            for (int kk = 0; kk < KK; ++kk) af[m][kk] = *(const f16x8*)(Al + aoff[m][kk]);
#pragma unroll
        for (int n = 0; n < NR; ++n)
#pragma unroll
            for (int kk = 0; kk < KK; ++kk) bfr[n][kk] = *(const f16x8*)(Bl + boff[n][kk]);
#pragma unroll
        for (int kk = 0; kk < KK; ++kk)
#pragma unroll
            for (int m = 0; m < MR; ++m)
#pragma unroll
                for (int n = 0; n < NR; ++n)
                    acc[m][n] = __builtin_amdgcn_mfma_f32_16x16x32_f16(af[m][kk], bfr[n][kk], acc[m][n], 0, 0, 0);
        __syncthreads();                // drains vmcnt+lgkmcnt, swap safe
        buf ^= 1;
    }

    const long long cOff = (long long)zh * sChi + (long long)zl * sClo;
    const int rbase = (lane >> 4) * 4;  // C/D: row=(lane>>4)*4+r, col=lane&15
#pragma unroll
    for (int m = 0; m < MR; ++m) {
        const int row = m0 + wr * WMT + m * 16 + rbase;
#pragma unroll
        for (int n = 0; n < NR; ++n) {
            const int col = n0 + wc * WNT + n * 16 + l15;
            const float bb = bias ? bias[col] : 0.0f;
            if (VOUT && col >= 1024) {  // V head -> transposed f16x4 store
                const int hh = (col - 1024) >> 6, dv = (col - 1024) & 63;
                const int bb_ = row >> 9, t0 = row & 511;
                f16x4 v4;
#pragma unroll
                for (int r = 0; r < 4; ++r) v4[r] = (f16_t)(acc[m][n][r] + bb);
                *(f16x4*)&vt[((long long)((bb_ * 8 + hh) * 64 + dv)) * 512 + t0] = v4;
            } else {
#pragma unroll
                for (int r = 0; r < 4; ++r) {
                    float v = acc[m][n][r] + bb;
                    if (RELU) v = fmaxf(v, 0.0f);
                    const long long idx = cOff + (long long)(row + r) * ldc + col;
                    if (OUTF16) ((f16_t*)Cout)[idx] = (f16_t)v;
                    else        ((float*)Cout)[idx] = v;
                }
            }
        }
    }
}

// ------- flash attention per (b,h, 64-q tile): softmax(Q K^T) V -> ao -------
// v1 structure (round 8): K,Q staged via global_load_lds (coalesced), one
// barrier after staging; per-wave P buffer; V frags from global (L2).
// + T5 setprio around MFMA clusters.
__global__ void __launch_bounds__(256)
attn_flash_kernel(const f16_t* __restrict__ qkv, const f16_t* __restrict__ Vt,
                  f16_t* __restrict__ ao)
{
    __shared__ __align__(16) f16_t Ks[512 * 64];   // 64KB
    __shared__ __align__(16) f16_t Qs[64 * 64];    //  8KB
    __shared__ __align__(16) f16_t Ps[4][16 * 64]; //  8KB (per-wave private)
    const int tid = threadIdx.x, wid = tid >> 6, lane = tid & 63;
    const int l15 = lane & 15, g = lane >> 4;
    const int z = blockIdx.y, b = z >> 3, hh = z & 7;
    const int q0 = blockIdx.x * 64;
    const f16_t* Kbase = qkv + (long long)b * 512 * 1536 + 512 + hh * 64;
    const f16_t* Qbase = qkv + (long long)(b * 512 + q0) * 1536 + hh * 64;
    const f16_t* Vbase = Vt + (long long)z * 32768;

    // stage K[512][64] and Q[64][64]; linear LDS dest, inverse-swizzled source
#pragma unroll
    for (int i = 0; i < 16; ++i) {
        const int c = i * 256 + tid, t = c >> 3, j = c & 7;
        gl_lds16(Kbase + (long long)t * 1536 + ((j ^ (t & 7)) << 3), Ks + c * 8);
    }
#pragma unroll
    for (int i = 0; i < 2; ++i) {
        const int c = i * 256 + tid, t = c >> 3, j = c & 7;
        gl_lds16(Qbase + (long long)t * 1536 + ((j ^ (t & 7)) << 3), Qs + c * 8);
    }
    __syncthreads();

    // hoisted Q B-frags: this wave's q rows = wid*16 + l15
    const int q = wid * 16 + l15;
    f16x8 qf[2];
#pragma unroll
    for (int k = 0; k < 2; ++k)
        qf[k] = *(const f16x8*)(Qs + q * 64 + (((k * 4 + g) ^ (l15 & 7)) << 3));

    f32x4 ov[4] = {};                   // O rows q=g*4+r, cols dv=n*16+l15
    float m_run = -1e30f, l_run = 0.0f;
    f16_t* Pw = &Ps[wid][0];

    for (int ck = 0; ck < 8; ++ck) {
        const int kc0 = ck * 64;
        f16x8 vf[4][2];
#pragma unroll
        for (int n = 0; n < 4; ++n)
#pragma unroll
            for (int k = 0; k < 2; ++k)
                vf[n][k] = *(const f16x8*)(Vbase + (n * 16 + l15) * 512 + kc0 + k * 32 + g * 8);
        // S^T = K_chunk . Q^T : rows=keys, cols=q
        f32x4 s[4] = {};
        __builtin_amdgcn_s_setprio(1);
#pragma unroll
        for (int k = 0; k < 2; ++k)
#pragma unroll
            for (int m = 0; m < 4; ++m) {
                const int key = kc0 + m * 16 + l15;
                const f16x8 a = *(const f16x8*)(Ks + key * 64 + (((k * 4 + g) ^ (key & 7)) << 3));
                s[m] = __builtin_amdgcn_mfma_f32_16x16x32_f16(a, qf[k], s[m], 0, 0, 0);
            }
        __builtin_amdgcn_s_setprio(0);
        // online softmax over keys for q = l15
        float cmax = -1e30f;
#pragma unroll
        for (int m = 0; m < 4; ++m)
#pragma unroll
            for (int r = 0; r < 4; ++r) cmax = fmaxf(cmax, s[m][r]);
        cmax = fmaxf(cmax, __shfl_xor(cmax, 16, 64));
        cmax = fmaxf(cmax, __shfl_xor(cmax, 32, 64));
        const float mnew = fmaxf(m_run, cmax);
        const float corr = __expf(m_run - mnew);
        float csum = 0.0f;
#pragma unroll
        for (int m = 0; m < 4; ++m) {
            f16x4 p4;
#pragma unroll
            for (int r = 0; r < 4; ++r) {
                const float pe = __expf(s[m][r] - mnew);
                csum += pe;
                p4[r] = (f16_t)pe;
            }
            *(f16x4*)(Pw + l15 * 64 + ((((m * 2 + (g >> 1)) ^ (l15 & 7))) << 3) + ((g & 1) << 2)) = p4;
        }
        csum += __shfl_xor(csum, 16, 64);
        csum += __shfl_xor(csum, 32, 64);
        l_run = l_run * corr + csum;
        m_run = mnew;
        float cr[4];
#pragma unroll
        for (int r = 0; r < 4; ++r) cr[r] = __shfl(corr, g * 4 + r, 64);
#pragma unroll
        for (int n = 0; n < 4; ++n)
#pragma unroll
            for (int r = 0; r < 4; ++r) ov[n][r] *= cr[r];
#pragma unroll
        for (int k = 0; k < 2; ++k) {
            const f16x8 pf = *(const f16x8*)(Pw + l15 * 64 + (((k * 4 + g) ^ (l15 & 7)) << 3));
            __builtin_amdgcn_s_setprio(1);
#pragma unroll
            for (int n = 0; n < 4; ++n)
                ov[n] = __builtin_amdgcn_mfma_f32_16x16x32_f16(pf, vf[n][k], ov[n], 0, 0, 0);
            __builtin_amdgcn_s_setprio(0);
        }
    }

    const float inv = 1.0f / l_run;
    float ir[4];
#pragma unroll
    for (int r = 0; r < 4; ++r) ir[r] = __shfl(inv, g * 4 + r, 64);
#pragma unroll
    for (int n = 0; n < 4; ++n)
#pragma unroll
        for (int r = 0; r < 4; ++r) {
            const long long row = b * 512 + q0 + wid * 16 + g * 4 + r;
            ao[row * 512 + hh * 64 + n * 16 + l15] = (f16_t)(ov[n][r] * ir[r]);
        }
}

// ---- fused setup: wconv (18432 blks) + embed (4096) + biascat (36) --------
__global__ void __launch_bounds__(256)
setup_kernel(const float* __restrict__ Wq, const float* __restrict__ Wk,
             const float* __restrict__ Wv, const float* __restrict__ Wo,
             const float* __restrict__ W1, const float* __restrict__ W2,
             f16_t* __restrict__ wT,
             const int* __restrict__ xt, const float* __restrict__ emb,
             f16_t* __restrict__ hb,
             const float* __restrict__ bq, const float* __restrict__ bk,
             const float* __restrict__ bv, float* __restrict__ qkvb)
{
    __shared__ float tile[32][33];
    const int blk = blockIdx.x;
    const int tid = threadIdx.x;
    if (blk < 18432) {                  // ---- weight convert+transpose
        const int layer = blk / 3072;
        const int r     = blk % 3072;
        const float* src; f16_t* dst; int R, C, tt;
        if (r < 1024) {
            const int mat = r >> 8; tt = r & 255; R = 512; C = 512;
            const float* s4 = (mat == 0) ? Wq : (mat == 1) ? Wk : (mat == 2) ? Wv : Wo;
            src = s4 + (long long)layer * 262144;
            dst = wT + (long long)layer * LSTR + (long long)mat * 262144;
        } else if (r < 2048) {
            tt = r - 1024; R = 512; C = 2048;
            src = W1 + (long long)layer * 1048576;
            dst = wT + (long long)layer * LSTR + 1048576;
        } else {
            tt = r - 2048; R = 2048; C = 512;
            src = W2 + (long long)layer * 1048576;
            dst = wT + (long long)layer * LSTR + 2097152;
        }
        const int tC = C >> 5;
        const int tr = tt / tC, tc = tt % tC;
        const int r0 = tr * 32, c0 = tc * 32;
        const int tx = tid & 31, ty = tid >> 5;
#pragma unroll
        for (int i = 0; i < 4; ++i)
            tile[ty + 8 * i][tx] = src[(long long)(r0 + ty + 8 * i) * C + c0 + tx];
        __syncthreads();
#pragma unroll
        for (int i = 0; i < 4; ++i)
            dst[(long long)(c0 + ty + 8 * i) * R + r0 + tx] = (f16_t)tile[tx][ty + 8 * i];
    } else if (blk < 18432 + 4096) {    // ---- embedding + sinusoidal PE
        const int row = blk - 18432;
        const int t   = row & 511;
        const int tok = xt[row];
#pragma unroll
        for (int s = 0; s < 2; ++s) {
            const int d = tid + s * 256;
            const int i = d >> 1;
            const float inv = expf((float)(2 * i) * (-9.210340371976184f / 512.0f));
            const float ang = (float)t * inv;
            const float pe  = (d & 1) ? cosf(ang) : sinf(ang);
            hb[(long long)row * 512 + d] = (f16_t)(emb[(long long)tok * 512 + d] + pe);
        }
    } else {                            // ---- bias concat
        const int i = (blk - 22528) * 256 + tid;
        if (i < 9216) {
            const int l = i / 1536, c = i % 1536;
            float v;
            if (c < 512)       v = bq[l * 512 + c];
            else if (c < 1024) v = bk[l * 512 + c - 512];
            else               v = bv[l * 512 + c - 1024];
            qkvb[i] = v;
        }
    }
}

// ---- hb = LN( sum_{s<ns} X[s] + bias + hb ); wave-per-row, no barriers -----
__global__ void __launch_bounds__(256)
add_ln_kernel(const f16_t* __restrict__ X, int ns, long long sstr,
              const float* __restrict__ bias,
              const float* __restrict__ g, const float* __restrict__ b,
              f16_t* __restrict__ Hf)
{
    const int wid = threadIdx.x >> 6, lane = threadIdx.x & 63;
    const long long row = (long long)blockIdx.x * 4 + wid;
    f16_t* h = Hf + row * 512;
    const int c0 = lane * 8;
    const f16x8 hv = *(const f16x8*)&h[c0];
    float v[8];
#pragma unroll
    for (int e = 0; e < 8; ++e) v[e] = (float)hv[e] + bias[c0 + e];
    for (int s = 0; s < ns; ++s) {
        const f16x8 xv = *(const f16x8*)&X[s * sstr + row * 512 + c0];
#pragma unroll
        for (int e = 0; e < 8; ++e) v[e] += (float)xv[e];
    }
    float sum = 0.0f, sq = 0.0f;
#pragma unroll
    for (int e = 0; e < 8; ++e) { sum += v[e]; sq += v[e] * v[e]; }
#pragma unroll
    for (int o = 1; o < 64; o <<= 1) {
        sum += __shfl_xor(sum, o, 64);
        sq  += __shfl_xor(sq,  o, 64);
    }
    const float mu = sum * (1.0f / 512.0f);
    float var = sq * (1.0f / 512.0f) - mu * mu;
    var = fmaxf(var, 0.0f);
    const float rs = rsqrtf(var + 1e-5f);
    f16x8 o8;
#pragma unroll
    for (int e = 0; e < 8; ++e)
        o8[e] = (f16_t)(g[c0 + e] * (v[e] - mu) * rs + b[c0 + e]);
    *(f16x8*)&h[c0] = o8;
}

// ---------------- classifier head: split reduction (hb f16) -----------------
__global__ void head_partial_kernel(const f16_t* __restrict__ hb, const float* __restrict__ Wout,
                                    float* __restrict__ partials)
{
    const int blk = blockIdx.x;         // 8 b * 64 chunks
    const int b = blk >> 6, chunk = blk & 63;
    const int tid = threadIdx.x;
    const f16_t* hp = hb + (long long)b * 262144 + (long long)chunk * 4096;
    float a0 = 0, a1 = 0, a2 = 0, a3 = 0, a4 = 0;
    for (int it = 0; it < 16; ++it) {
        const int idx = it * 256 + tid;
        const float hv = (float)hp[idx];
        const float* w = Wout + ((long long)chunk * 4096 + idx) * 5;
        a0 += hv * w[0]; a1 += hv * w[1]; a2 += hv * w[2]; a3 += hv * w[3]; a4 += hv * w[4];
    }
#pragma unroll
    for (int o = 32; o > 0; o >>= 1) {
        a0 += __shfl_down(a0, o, 64); a1 += __shfl_down(a1, o, 64); a2 += __shfl_down(a2, o, 64);
        a3 += __shfl_down(a3, o, 64); a4 += __shfl_down(a4, o, 64);
    }
    __shared__ float sm[4][5];
    const int lane = tid & 63, w = tid >> 6;
    if (lane == 0) { sm[w][0] = a0; sm[w][1] = a1; sm[w][2] = a2; sm[w][3] = a3; sm[w][4] = a4; }
    __syncthreads();
    if (tid < 5)
        partials[(long long)blk * 5 + tid] = sm[0][tid] + sm[1][tid] + sm[2][tid] + sm[3][tid];
}

__global__ void head_final_kernel(const float* __restrict__ partials, const float* __restrict__ bout,
                                  float* __restrict__ out)
{
    const int tid = threadIdx.x;
    if (tid >= 40) return;
    const int b = tid / 5, c = tid % 5;
    float s = bout[c];
    const float* p = partials + (long long)b * 64 * 5 + c;
    for (int ck = 0; ck < 64; ++ck) s += p[ck * 5];
    out[tid] = s;   // reference output dtype is float32
}

// ---------------------------------------------------------------------------
extern "C" void kernel_launch(void* const* d_in, const int* in_sizes, int n_in,
                              void* d_out, int out_size, void* d_ws, size_t ws_size,
                              hipStream_t stream)
{
    (void)in_sizes; (void)n_in; (void)out_size; (void)ws_size;
    const int*   x_tok = (const int*)  d_in[0];
    const float* emb   = (const float*)d_in[2];
    const float* Wq    = (const float*)d_in[3];
    const float* bq    = (const float*)d_in[4];
    const float* Wk    = (const float*)d_in[5];
    const float* bk    = (const float*)d_in[6];
    const float* Wv    = (const float*)d_in[7];
    const float* bv    = (const float*)d_in[8];
    const float* Wo    = (const float*)d_in[9];
    const float* bo    = (const float*)d_in[10];
    const float* gma   = (const float*)d_in[11];
    const float* bta   = (const float*)d_in[12];
    const float* W1    = (const float*)d_in[13];
    const float* b1    = (const float*)d_in[14];
    const float* W2    = (const float*)d_in[15];
    const float* b2    = (const float*)d_in[16];
    const float* Wout  = (const float*)d_in[17];
    const float* bout  = (const float*)d_in[18];

    char* ws = (char*)d_ws;
    size_t off = 0;
    auto take = [&](size_t bytes) { char* p = ws + off; off += (bytes + 255) & ~(size_t)255; return p; };
    f16_t* wT    = (f16_t*)take(18874368ULL * 2);  // transposed f16 weights
    f16_t* hb    = (f16_t*)take(2097152ULL * 2);   // residual stream (f16)
    f16_t* qkv   = (f16_t*)take(6291456ULL * 2);   // [4096][1536] (Q,K used)
    f16_t* Vt    = (f16_t*)take(2097152ULL * 2);   // [64][64][512]
    f16_t* ao    = (f16_t*)take(2097152ULL * 2);   // attn out [4096][512]
    f16_t* f1    = (f16_t*)take(8388608ULL * 2);   // ffn hidden [4096][2048]
    f16_t* t16   = (f16_t*)take(4ULL * 2097152ULL * 2); // split-K f16 partials
    float* qkvb  = (float*)take(9216ULL * 4);
    float* parts = (float*)take(2560ULL * 4);

    setup_kernel<<<dim3(22564), 256, 0, stream>>>(Wq, Wk, Wv, Wo, W1, W2, wT,
                                                  x_tok, emb, hb, bq, bk, bv, qkvb);

    for (int l = 0; l < 6; ++l) {
        const f16_t* wl = wT + (long long)l * LSTR;
        // QKV: [4096,512]@[512,1536]; V heads written transposed to Vt
        gemm_kernel<64,128,64,2,2,1,0,1><<<dim3(64,12,1),256,0,stream>>>(hb, wl, qkvb + l*1536,
            qkv, Vt, 4096,1536,512, 512,512,1536, 1, 0,0,0,0,0,0);
        // flash attention (v1 structure + setprio): softmax(QK^T)V -> ao
        attn_flash_kernel<<<dim3(8,64),256,0,stream>>>(qkv, Vt, ao);
        // O proj: 64x128 split-K x2 (512 blocks) -> t16 slices
        gemm_kernel<64,128,64,2,2,1,0,0><<<dim3(64,4,2),256,0,stream>>>(ao, wl + 786432, nullptr,
            t16, nullptr, 4096,512,256, 512,512,512, 1, 256LL,0LL, 256LL,0LL, 2097152LL,0LL);
        add_ln_kernel<<<dim3(1024),256,0,stream>>>(t16, 2, 2097152LL, bo + l*512,
            gma + l*512, bta + l*512, hb);
        // FFN1 + relu -> f1 f16: 128x128/BK=32 (512 blocks, 2/CU uniform)
        gemm_kernel<128,128,32,2,2,1,1,0><<<dim3(32,16,1),256,0,stream>>>(hb, wl + 1048576, b1 + l*2048,
            f1, nullptr, 4096,2048,512, 512,512,2048, 1, 0,0,0,0,0,0);
        // FFN2: 128x128/BK=32 split-K x4 (512 blocks, 2/CU) -> t16 slices
        gemm_kernel<128,128,32,2,2,1,0,0><<<dim3(32,4,4),256,0,stream>>>(f1, wl + 2097152, nullptr,
            t16, nullptr, 4096,512,512, 2048,2048,512, 1, 512LL,0LL, 512LL,0LL, 2097152LL,0LL);
        add_ln_kernel<<<dim3(1024),256,0,stream>>>(t16, 4, 2097152LL, b2 + l*512,
            gma + l*512, bta + l*512, hb);
    }

    head_partial_kernel<<<dim3(512),256,0,stream>>>(hb, Wout, parts);
    head_final_kernel  <<<dim3(1),64,0,stream>>>(parts, bout, (float*)d_out);
}

// Round 11
// 561.202 us; speedup vs baseline: 1.1588x; 1.0047x over previous
//
#include <hip/hip_runtime.h>
#include <hip/hip_bf16.h>

// ---------------------------------------------------------------------------
// 6-layer transformer forward, MI355X. f16 MFMA compute, f32 stats.
// Round 11: setup wconv rewritten with 64x64 tiles (float4 reads, f16x4
//           coalesced transposed writes, conflict-free [64][65] LDS).
// ---------------------------------------------------------------------------

typedef _Float16 f16_t;
typedef _Float16 f16x8 __attribute__((ext_vector_type(8)));
typedef _Float16 f16x4 __attribute__((ext_vector_type(4)));
typedef _Float16 f16x2 __attribute__((ext_vector_type(2)));
typedef float    f32x4 __attribute__((ext_vector_type(4)));

#define LSTR 3145728LL  // per-layer transposed-weight stride (f16 elems)

__device__ __forceinline__ void gl_lds16(const f16_t* g, f16_t* l) {
    __builtin_amdgcn_global_load_lds(
        (const __attribute__((address_space(1))) unsigned int*)g,
        (__attribute__((address_space(3))) unsigned int*)l, 16, 0, 0);
}

// ---------------- pipelined batched GEMM: C = A[M,K] * (Bt[N,K])^T + bias ---
// A, Bt f16 row-major. blockIdx.z -> zh=z/zmod, zl=z%zmod; per-operand strides.
// Split-K via zmod=1: sAhi/sBhi = K-slice offset, sChi = C-slice stride.
// LDS: linear dest (global_load_lds), XOR-swizzled 16B k-chunk on BOTH the
// global source and the LDS read offset (rule #21). BK=64: swz=row&7;
// BK=32: swz=(row>>1)&3.
// VOUT=1 (QKV): cols>=1024 are V heads -> written transposed to vt
// ([b*8+h][64][512]) as f16x4 (4 consecutive t per fragment); qkv gets Q,K.
template<int BM, int BN, int BK, int WR, int WC, int OUTF16, int RELU, int VOUT>
__global__ void __launch_bounds__(256)
gemm_kernel(const f16_t* __restrict__ A, const f16_t* __restrict__ B,
            const float* __restrict__ bias, void* __restrict__ Cout,
            f16_t* __restrict__ vt,
            int M, int N, int K, int lda, int ldb, int ldc, int zmod,
            long long sAhi, long long sAlo, long long sBhi, long long sBlo,
            long long sChi, long long sClo)
{
    constexpr int WMT = BM / WR;
    constexpr int WNT = BN / WC;
    constexpr int MR  = WMT / 16;
    constexpr int NR  = WNT / 16;
    constexpr int KK  = BK / 32;        // 16x16x32 MFMA k-substeps per K-step
    constexpr int CPR = BK / 8;         // 16B chunks per LDS row
    constexpr int RS  = (BK == 32) ? 1 : 0;
    constexpr int IA  = BM * BK / 2048; // global_load_lds issues per thread
    constexpr int IB  = BN * BK / 2048;
    __shared__ __align__(16) f16_t As[2][BM][BK];
    __shared__ __align__(16) f16_t Bs[2][BN][BK];

    const int tid  = threadIdx.x;
    const int wid  = tid >> 6, lane = tid & 63;
    const int wr   = wid / WC, wc = wid % WC;
    const int z    = blockIdx.z;
    const int zh   = z / zmod, zl = z % zmod;
    const f16_t* Ab = A + (long long)zh * sAhi + (long long)zl * sAlo;
    const f16_t* Bb = B + (long long)zh * sBhi + (long long)zl * sBlo;
    const int m0 = blockIdx.x * BM;
    const int n0 = blockIdx.y * BN;

    f32x4 acc[MR][NR] = {};

    // ---- staging addresses: chunk c=i*256+tid; row=c/CPR, j=c%CPR, j^=swz
    const f16_t* srcA[IA]; const f16_t* srcB[IB];
#pragma unroll
    for (int i = 0; i < IA; ++i) {
        const int c = i * 256 + tid, row = c / CPR;
        const int kch = (c % CPR) ^ ((row >> RS) & (CPR - 1));
        srcA[i] = Ab + (long long)(m0 + row) * lda + kch * 8;
    }
#pragma unroll
    for (int i = 0; i < IB; ++i) {
        const int c = i * 256 + tid, row = c / CPR;
        const int kch = (c % CPR) ^ ((row >> RS) & (CPR - 1));
        srcB[i] = Bb + (long long)(n0 + row) * ldb + kch * 8;
    }
    auto stage = [&](int bf_, int t) {
        const int k0 = t * BK;
#pragma unroll
        for (int i = 0; i < IA; ++i)
            gl_lds16(srcA[i] + k0, &As[bf_][0][0] + (i * 256 + wid * 64) * 8);
#pragma unroll
        for (int i = 0; i < IB; ++i)
            gl_lds16(srcB[i] + k0, &Bs[bf_][0][0] + (i * 256 + wid * 64) * 8);
    };

    // ---- fragment read offsets (bytes), swizzled to match staged layout
    const int l15 = lane & 15;
    const int g   = lane >> 4;
    int aoff[MR][KK], boff[NR][KK];
#pragma unroll
    for (int m = 0; m < MR; ++m) {
        const int row = wr * WMT + m * 16 + l15;
        const int swz = ((row >> RS) & (CPR - 1)) << 4;
#pragma unroll
        for (int kk = 0; kk < KK; ++kk)
            aoff[m][kk] = ((row * BK + kk * 32 + g * 8) * 2) ^ swz;
    }
#pragma unroll
    for (int n = 0; n < NR; ++n) {
        const int row = wc * WNT + n * 16 + l15;
        const int swz = ((row >> RS) & (CPR - 1)) << 4;
#pragma unroll
        for (int kk = 0; kk < KK; ++kk)
            boff[n][kk] = ((row * BK + kk * 32 + g * 8) * 2) ^ swz;
    }

    const int NT = K / BK;
    stage(0, 0);
    __syncthreads();                    // drains vmcnt before barrier

    int buf = 0;
    for (int t = 0; t < NT; ++t) {
        if (t + 1 < NT) stage(buf ^ 1, t + 1);   // loads fly during MFMA
        const char* Al = (const char*)&As[buf][0][0];
        const char* Bl = (const char*)&Bs[buf][0][0];
        f16x8 af[MR][KK], bfr[NR][KK];
#pragma unroll
        for (int m = 0; m < MR; ++m)
#pragma unroll
            for (int kk = 0; kk < KK; ++kk) af[m][kk] = *(const f16x8*)(Al + aoff[m][kk]);
#pragma unroll
        for (int n = 0; n < NR; ++n)
#pragma unroll
            for (int kk = 0; kk < KK; ++kk) bfr[n][kk] = *(const f16x8*)(Bl + boff[n][kk]);
#pragma unroll
        for (int kk = 0; kk < KK; ++kk)
#pragma unroll
            for (int m = 0; m < MR; ++m)
#pragma unroll
                for (int n = 0; n < NR; ++n)
                    acc[m][n] = __builtin_amdgcn_mfma_f32_16x16x32_f16(af[m][kk], bfr[n][kk], acc[m][n], 0, 0, 0);
        __syncthreads();                // drains vmcnt+lgkmcnt, swap safe
        buf ^= 1;
    }

    const long long cOff = (long long)zh * sChi + (long long)zl * sClo;
    const int rbase = (lane >> 4) * 4;  // C/D: row=(lane>>4)*4+r, col=lane&15
#pragma unroll
    for (int m = 0; m < MR; ++m) {
        const int row = m0 + wr * WMT + m * 16 + rbase;
#pragma unroll
        for (int n = 0; n < NR; ++n) {
            const int col = n0 + wc * WNT + n * 16 + l15;
            const float bb = bias ? bias[col] : 0.0f;
            if (VOUT && col >= 1024) {  // V head -> transposed f16x4 store
                const int hh = (col - 1024) >> 6, dv = (col - 1024) & 63;
                const int bb_ = row >> 9, t0 = row & 511;
                f16x4 v4;
#pragma unroll
                for (int r = 0; r < 4; ++r) v4[r] = (f16_t)(acc[m][n][r] + bb);
                *(f16x4*)&vt[((long long)((bb_ * 8 + hh) * 64 + dv)) * 512 + t0] = v4;
            } else {
#pragma unroll
                for (int r = 0; r < 4; ++r) {
                    float v = acc[m][n][r] + bb;
                    if (RELU) v = fmaxf(v, 0.0f);
                    const long long idx = cOff + (long long)(row + r) * ldc + col;
                    if (OUTF16) ((f16_t*)Cout)[idx] = (f16_t)v;
                    else        ((float*)Cout)[idx] = v;
                }
            }
        }
    }
}

// ------- flash attention per (b,h, 64-q tile): softmax(Q K^T) V -> ao -------
// K,Q staged via global_load_lds (coalesced), one barrier after staging;
// per-wave P buffer; V frags from global (L2). setprio on MFMA clusters.
__global__ void __launch_bounds__(256)
attn_flash_kernel(const f16_t* __restrict__ qkv, const f16_t* __restrict__ Vt,
                  f16_t* __restrict__ ao)
{
    __shared__ __align__(16) f16_t Ks[512 * 64];   // 64KB
    __shared__ __align__(16) f16_t Qs[64 * 64];    //  8KB
    __shared__ __align__(16) f16_t Ps[4][16 * 64]; //  8KB (per-wave private)
    const int tid = threadIdx.x, wid = tid >> 6, lane = tid & 63;
    const int l15 = lane & 15, g = lane >> 4;
    const int z = blockIdx.y, b = z >> 3, hh = z & 7;
    const int q0 = blockIdx.x * 64;
    const f16_t* Kbase = qkv + (long long)b * 512 * 1536 + 512 + hh * 64;
    const f16_t* Qbase = qkv + (long long)(b * 512 + q0) * 1536 + hh * 64;
    const f16_t* Vbase = Vt + (long long)z * 32768;

    // stage K[512][64] and Q[64][64]; linear LDS dest, inverse-swizzled source
#pragma unroll
    for (int i = 0; i < 16; ++i) {
        const int c = i * 256 + tid, t = c >> 3, j = c & 7;
        gl_lds16(Kbase + (long long)t * 1536 + ((j ^ (t & 7)) << 3), Ks + c * 8);
    }
#pragma unroll
    for (int i = 0; i < 2; ++i) {
        const int c = i * 256 + tid, t = c >> 3, j = c & 7;
        gl_lds16(Qbase + (long long)t * 1536 + ((j ^ (t & 7)) << 3), Qs + c * 8);
    }
    __syncthreads();

    // hoisted Q B-frags: this wave's q rows = wid*16 + l15
    const int q = wid * 16 + l15;
    f16x8 qf[2];
#pragma unroll
    for (int k = 0; k < 2; ++k)
        qf[k] = *(const f16x8*)(Qs + q * 64 + (((k * 4 + g) ^ (l15 & 7)) << 3));

    f32x4 ov[4] = {};                   // O rows q=g*4+r, cols dv=n*16+l15
    float m_run = -1e30f, l_run = 0.0f;
    f16_t* Pw = &Ps[wid][0];

    for (int ck = 0; ck < 8; ++ck) {
        const int kc0 = ck * 64;
        f16x8 vf[4][2];
#pragma unroll
        for (int n = 0; n < 4; ++n)
#pragma unroll
            for (int k = 0; k < 2; ++k)
                vf[n][k] = *(const f16x8*)(Vbase + (n * 16 + l15) * 512 + kc0 + k * 32 + g * 8);
        // S^T = K_chunk . Q^T : rows=keys, cols=q
        f32x4 s[4] = {};
        __builtin_amdgcn_s_setprio(1);
#pragma unroll
        for (int k = 0; k < 2; ++k)
#pragma unroll
            for (int m = 0; m < 4; ++m) {
                const int key = kc0 + m * 16 + l15;
                const f16x8 a = *(const f16x8*)(Ks + key * 64 + (((k * 4 + g) ^ (key & 7)) << 3));
                s[m] = __builtin_amdgcn_mfma_f32_16x16x32_f16(a, qf[k], s[m], 0, 0, 0);
            }
        __builtin_amdgcn_s_setprio(0);
        // online softmax over keys for q = l15
        float cmax = -1e30f;
#pragma unroll
        for (int m = 0; m < 4; ++m)
#pragma unroll
            for (int r = 0; r < 4; ++r) cmax = fmaxf(cmax, s[m][r]);
        cmax = fmaxf(cmax, __shfl_xor(cmax, 16, 64));
        cmax = fmaxf(cmax, __shfl_xor(cmax, 32, 64));
        const float mnew = fmaxf(m_run, cmax);
        const float corr = __expf(m_run - mnew);
        float csum = 0.0f;
#pragma unroll
        for (int m = 0; m < 4; ++m) {
            f16x4 p4;
#pragma unroll
            for (int r = 0; r < 4; ++r) {
                const float pe = __expf(s[m][r] - mnew);
                csum += pe;
                p4[r] = (f16_t)pe;
            }
            *(f16x4*)(Pw + l15 * 64 + ((((m * 2 + (g >> 1)) ^ (l15 & 7))) << 3) + ((g & 1) << 2)) = p4;
        }
        csum += __shfl_xor(csum, 16, 64);
        csum += __shfl_xor(csum, 32, 64);
        l_run = l_run * corr + csum;
        m_run = mnew;
        float cr[4];
#pragma unroll
        for (int r = 0; r < 4; ++r) cr[r] = __shfl(corr, g * 4 + r, 64);
#pragma unroll
        for (int n = 0; n < 4; ++n)
#pragma unroll
            for (int r = 0; r < 4; ++r) ov[n][r] *= cr[r];
#pragma unroll
        for (int k = 0; k < 2; ++k) {
            const f16x8 pf = *(const f16x8*)(Pw + l15 * 64 + (((k * 4 + g) ^ (l15 & 7)) << 3));
            __builtin_amdgcn_s_setprio(1);
#pragma unroll
            for (int n = 0; n < 4; ++n)
                ov[n] = __builtin_amdgcn_mfma_f32_16x16x32_f16(pf, vf[n][k], ov[n], 0, 0, 0);
            __builtin_amdgcn_s_setprio(0);
        }
    }

    const float inv = 1.0f / l_run;
    float ir[4];
#pragma unroll
    for (int r = 0; r < 4; ++r) ir[r] = __shfl(inv, g * 4 + r, 64);
#pragma unroll
    for (int n = 0; n < 4; ++n)
#pragma unroll
        for (int r = 0; r < 4; ++r) {
            const long long row = b * 512 + q0 + wid * 16 + g * 4 + r;
            ao[row * 512 + hh * 64 + n * 16 + l15] = (f16_t)(ov[n][r] * ir[r]);
        }
}

// ---- fused setup: wconv 64x64 (4608 blks) + embed (4096) + biascat (36) ----
// wconv: float4 reads (256B/row), f16x4 transposed writes (128B/row),
// LDS float[64][65] -> transposed read is 2-way bank aliased (free, m136).
__global__ void __launch_bounds__(256)
setup_kernel(const float* __restrict__ Wq, const float* __restrict__ Wk,
             const float* __restrict__ Wv, const float* __restrict__ Wo,
             const float* __restrict__ W1, const float* __restrict__ W2,
             f16_t* __restrict__ wT,
             const int* __restrict__ xt, const float* __restrict__ emb,
             f16_t* __restrict__ hb,
             const float* __restrict__ bq, const float* __restrict__ bk,
             const float* __restrict__ bv, float* __restrict__ qkvb)
{
    __shared__ float tile[64][65];
    const int blk = blockIdx.x;
    const int tid = threadIdx.x;
    if (blk < 4608) {                   // ---- weight convert+transpose 64x64
        const int layer = blk / 768;
        const int r     = blk % 768;
        const float* src; f16_t* dst; int R, C, tt;
        if (r < 256) {                  // Wq,Wk,Wv,Wo: [512,512], 64 tiles each
            const int mat = r >> 6; tt = r & 63; R = 512; C = 512;
            const float* s4 = (mat == 0) ? Wq : (mat == 1) ? Wk : (mat == 2) ? Wv : Wo;
            src = s4 + (long long)layer * 262144;
            dst = wT + (long long)layer * LSTR + (long long)mat * 262144;
        } else if (r < 512) {           // W1: [512,2048]
            tt = r - 256; R = 512; C = 2048;
            src = W1 + (long long)layer * 1048576;
            dst = wT + (long long)layer * LSTR + 1048576;
        } else {                        // W2: [2048,512]
            tt = r - 512; R = 2048; C = 512;
            src = W2 + (long long)layer * 1048576;
            dst = wT + (long long)layer * LSTR + 2097152;
        }
        const int tC = C >> 6;
        const int tr = tt / tC, tc = tt % tC;
        const int r0 = tr * 64, c0 = tc * 64;
        const int tx = tid & 15, ty = tid >> 4;
#pragma unroll
        for (int i = 0; i < 4; ++i)
            *(float4*)&tile[ty + 16 * i][tx * 4] =
                *(const float4*)&src[(long long)(r0 + ty + 16 * i) * C + c0 + tx * 4];
        __syncthreads();
#pragma unroll
        for (int i = 0; i < 4; ++i) {
            f16x4 o;
#pragma unroll
            for (int e = 0; e < 4; ++e) o[e] = (f16_t)tile[tx * 4 + e][ty + 16 * i];
            *(f16x4*)&dst[(long long)(c0 + ty + 16 * i) * R + r0 + tx * 4] = o;
        }
    } else if (blk < 4608 + 4096) {     // ---- embedding + sinusoidal PE
        const int row = blk - 4608;
        const int t   = row & 511;
        const int tok = xt[row];
#pragma unroll
        for (int s = 0; s < 2; ++s) {
            const int d = tid + s * 256;
            const int i = d >> 1;
            const float inv = expf((float)(2 * i) * (-9.210340371976184f / 512.0f));
            const float ang = (float)t * inv;
            const float pe  = (d & 1) ? cosf(ang) : sinf(ang);
            hb[(long long)row * 512 + d] = (f16_t)(emb[(long long)tok * 512 + d] + pe);
        }
    } else {                            // ---- bias concat
        const int i = (blk - 8704) * 256 + tid;
        if (i < 9216) {
            const int l = i / 1536, c = i % 1536;
            float v;
            if (c < 512)       v = bq[l * 512 + c];
            else if (c < 1024) v = bk[l * 512 + c - 512];
            else               v = bv[l * 512 + c - 1024];
            qkvb[i] = v;
        }
    }
}

// ---- hb = LN( sum_{s<ns} X[s] + bias + hb ); wave-per-row, no barriers -----
__global__ void __launch_bounds__(256)
add_ln_kernel(const f16_t* __restrict__ X, int ns, long long sstr,
              const float* __restrict__ bias,
              const float* __restrict__ g, const float* __restrict__ b,
              f16_t* __restrict__ Hf)
{
    const int wid = threadIdx.x >> 6, lane = threadIdx.x & 63;
    const long long row = (long long)blockIdx.x * 4 + wid;
    f16_t* h = Hf + row * 512;
    const int c0 = lane * 8;
    const f16x8 hv = *(const f16x8*)&h[c0];
    float v[8];
#pragma unroll
    for (int e = 0; e < 8; ++e) v[e] = (float)hv[e] + bias[c0 + e];
    for (int s = 0; s < ns; ++s) {
        const f16x8 xv = *(const f16x8*)&X[s * sstr + row * 512 + c0];
#pragma unroll
        for (int e = 0; e < 8; ++e) v[e] += (float)xv[e];
    }
    float sum = 0.0f, sq = 0.0f;
#pragma unroll
    for (int e = 0; e < 8; ++e) { sum += v[e]; sq += v[e] * v[e]; }
#pragma unroll
    for (int o = 1; o < 64; o <<= 1) {
        sum += __shfl_xor(sum, o, 64);
        sq  += __shfl_xor(sq,  o, 64);
    }
    const float mu = sum * (1.0f / 512.0f);
    float var = sq * (1.0f / 512.0f) - mu * mu;
    var = fmaxf(var, 0.0f);
    const float rs = rsqrtf(var + 1e-5f);
    f16x8 o8;
#pragma unroll
    for (int e = 0; e < 8; ++e)
        o8[e] = (f16_t)(g[c0 + e] * (v[e] - mu) * rs + b[c0 + e]);
    *(f16x8*)&h[c0] = o8;
}

// ---------------- classifier head: split reduction (hb f16) -----------------
__global__ void head_partial_kernel(const f16_t* __restrict__ hb, const float* __restrict__ Wout,
                                    float* __restrict__ partials)
{
    const int blk = blockIdx.x;         // 8 b * 64 chunks
    const int b = blk >> 6, chunk = blk & 63;
    const int tid = threadIdx.x;
    const f16_t* hp = hb + (long long)b * 262144 + (long long)chunk * 4096;
    float a0 = 0, a1 = 0, a2 = 0, a3 = 0, a4 = 0;
    for (int it = 0; it < 16; ++it) {
        const int idx = it * 256 + tid;
        const float hv = (float)hp[idx];
        const float* w = Wout + ((long long)chunk * 4096 + idx) * 5;
        a0 += hv * w[0]; a1 += hv * w[1]; a2 += hv * w[2]; a3 += hv * w[3]; a4 += hv * w[4];
    }
#pragma unroll
    for (int o = 32; o > 0; o >>= 1) {
        a0 += __shfl_down(a0, o, 64); a1 += __shfl_down(a1, o, 64); a2 += __shfl_down(a2, o, 64);
        a3 += __shfl_down(a3, o, 64); a4 += __shfl_down(a4, o, 64);
    }
    __shared__ float sm[4][5];
    const int lane = tid & 63, w = tid >> 6;
    if (lane == 0) { sm[w][0] = a0; sm[w][1] = a1; sm[w][2] = a2; sm[w][3] = a3; sm[w][4] = a4; }
    __syncthreads();
    if (tid < 5)
        partials[(long long)blk * 5 + tid] = sm[0][tid] + sm[1][tid] + sm[2][tid] + sm[3][tid];
}

__global__ void head_final_kernel(const float* __restrict__ partials, const float* __restrict__ bout,
                                  float* __restrict__ out)
{
    const int tid = threadIdx.x;
    if (tid >= 40) return;
    const int b = tid / 5, c = tid % 5;
    float s = bout[c];
    const float* p = partials + (long long)b * 64 * 5 + c;
    for (int ck = 0; ck < 64; ++ck) s += p[ck * 5];
    out[tid] = s;   // reference output dtype is float32
}

// ---------------------------------------------------------------------------
extern "C" void kernel_launch(void* const* d_in, const int* in_sizes, int n_in,
                              void* d_out, int out_size, void* d_ws, size_t ws_size,
                              hipStream_t stream)
{
    (void)in_sizes; (void)n_in; (void)out_size; (void)ws_size;
    const int*   x_tok = (const int*)  d_in[0];
    const float* emb   = (const float*)d_in[2];
    const float* Wq    = (const float*)d_in[3];
    const float* bq    = (const float*)d_in[4];
    const float* Wk    = (const float*)d_in[5];
    const float* bk    = (const float*)d_in[6];
    const float* Wv    = (const float*)d_in[7];
    const float* bv    = (const float*)d_in[8];
    const float* Wo    = (const float*)d_in[9];
    const float* bo    = (const float*)d_in[10];
    const float* gma   = (const float*)d_in[11];
    const float* bta   = (const float*)d_in[12];
    const float* W1    = (const float*)d_in[13];
    const float* b1    = (const float*)d_in[14];
    const float* W2    = (const float*)d_in[15];
    const float* b2    = (const float*)d_in[16];
    const float* Wout  = (const float*)d_in[17];
    const float* bout  = (const float*)d_in[18];

    char* ws = (char*)d_ws;
    size_t off = 0;
    auto take = [&](size_t bytes) { char* p = ws + off; off += (bytes + 255) & ~(size_t)255; return p; };
    f16_t* wT    = (f16_t*)take(18874368ULL * 2);  // transposed f16 weights
    f16_t* hb    = (f16_t*)take(2097152ULL * 2);   // residual stream (f16)
    f16_t* qkv   = (f16_t*)take(6291456ULL * 2);   // [4096][1536] (Q,K used)
    f16_t* Vt    = (f16_t*)take(2097152ULL * 2);   // [64][64][512]
    f16_t* ao    = (f16_t*)take(2097152ULL * 2);   // attn out [4096][512]
    f16_t* f1    = (f16_t*)take(8388608ULL * 2);   // ffn hidden [4096][2048]
    f16_t* t16   = (f16_t*)take(4ULL * 2097152ULL * 2); // split-K f16 partials
    float* qkvb  = (float*)take(9216ULL * 4);
    float* parts = (float*)take(2560ULL * 4);

    setup_kernel<<<dim3(8740), 256, 0, stream>>>(Wq, Wk, Wv, Wo, W1, W2, wT,
                                                 x_tok, emb, hb, bq, bk, bv, qkvb);

    for (int l = 0; l < 6; ++l) {
        const f16_t* wl = wT + (long long)l * LSTR;
        // QKV: [4096,512]@[512,1536]; V heads written transposed to Vt
        gemm_kernel<64,128,64,2,2,1,0,1><<<dim3(64,12,1),256,0,stream>>>(hb, wl, qkvb + l*1536,
            qkv, Vt, 4096,1536,512, 512,512,1536, 1, 0,0,0,0,0,0);
        // flash attention: softmax(QK^T)V -> ao
        attn_flash_kernel<<<dim3(8,64),256,0,stream>>>(qkv, Vt, ao);
        // O proj: 64x128 split-K x2 (512 blocks) -> t16 slices
        gemm_kernel<64,128,64,2,2,1,0,0><<<dim3(64,4,2),256,0,stream>>>(ao, wl + 786432, nullptr,
            t16, nullptr, 4096,512,256, 512,512,512, 1, 256LL,0LL, 256LL,0LL, 2097152LL,0LL);
        add_ln_kernel<<<dim3(1024),256,0,stream>>>(t16, 2, 2097152LL, bo + l*512,
            gma + l*512, bta + l*512, hb);
        // FFN1 + relu -> f1 f16: 128x128/BK=32 (512 blocks, 2/CU uniform)
        gemm_kernel<128,128,32,2,2,1,1,0><<<dim3(32,16,1),256,0,stream>>>(hb, wl + 1048576, b1 + l*2048,
            f1, nullptr, 4096,2048,512, 512,512,2048, 1, 0,0,0,0,0,0);
        // FFN2: 128x128/BK=32 split-K x4 (512 blocks, 2/CU) -> t16 slices
        gemm_kernel<128,128,32,2,2,1,0,0><<<dim3(32,4,4),256,0,stream>>>(f1, wl + 2097152, nullptr,
            t16, nullptr, 4096,512,512, 2048,2048,512, 1, 512LL,0LL, 512LL,0LL, 2097152LL,0LL);
        add_ln_kernel<<<dim3(1024),256,0,stream>>>(t16, 4, 2097152LL, b2 + l*512,
            gma + l*512, bta + l*512, hb);
    }

    head_partial_kernel<<<dim3(512),256,0,stream>>>(hb, Wout, parts);
    head_final_kernel  <<<dim3(1),64,0,stream>>>(parts, bout, (float*)d_out);
}

// Round 12
// 557.709 us; speedup vs baseline: 1.1661x; 1.0063x over previous
//
#include <hip/hip_runtime.h>
#include <hip/hip_bf16.h>

// ---------------------------------------------------------------------------
// 6-layer transformer forward, MI355X. f16 MFMA compute, f32 stats.
// Round 12: flash v3 — K staged in 4 double-buffered 128-key chunks
//           (40KB LDS -> 4 blocks/CU, loads overlap compute), Q from global.
// ---------------------------------------------------------------------------

typedef _Float16 f16_t;
typedef _Float16 f16x8 __attribute__((ext_vector_type(8)));
typedef _Float16 f16x4 __attribute__((ext_vector_type(4)));
typedef _Float16 f16x2 __attribute__((ext_vector_type(2)));
typedef float    f32x4 __attribute__((ext_vector_type(4)));

#define LSTR 3145728LL  // per-layer transposed-weight stride (f16 elems)

__device__ __forceinline__ void gl_lds16(const f16_t* g, f16_t* l) {
    __builtin_amdgcn_global_load_lds(
        (const __attribute__((address_space(1))) unsigned int*)g,
        (__attribute__((address_space(3))) unsigned int*)l, 16, 0, 0);
}

// ---------------- pipelined batched GEMM: C = A[M,K] * (Bt[N,K])^T + bias ---
// A, Bt f16 row-major. blockIdx.z -> zh=z/zmod, zl=z%zmod; per-operand strides.
// Split-K via zmod=1: sAhi/sBhi = K-slice offset, sChi = C-slice stride.
// LDS: linear dest (global_load_lds), XOR-swizzled 16B k-chunk on BOTH the
// global source and the LDS read offset (rule #21). BK=64: swz=row&7;
// BK=32: swz=(row>>1)&3.
// VOUT=1 (QKV): cols>=1024 are V heads -> written transposed to vt
// ([b*8+h][64][512]) as f16x4 (4 consecutive t per fragment); qkv gets Q,K.
template<int BM, int BN, int BK, int WR, int WC, int OUTF16, int RELU, int VOUT>
__global__ void __launch_bounds__(256)
gemm_kernel(const f16_t* __restrict__ A, const f16_t* __restrict__ B,
            const float* __restrict__ bias, void* __restrict__ Cout,
            f16_t* __restrict__ vt,
            int M, int N, int K, int lda, int ldb, int ldc, int zmod,
            long long sAhi, long long sAlo, long long sBhi, long long sBlo,
            long long sChi, long long sClo)
{
    constexpr int WMT = BM / WR;
    constexpr int WNT = BN / WC;
    constexpr int MR  = WMT / 16;
    constexpr int NR  = WNT / 16;
    constexpr int KK  = BK / 32;        // 16x16x32 MFMA k-substeps per K-step
    constexpr int CPR = BK / 8;         // 16B chunks per LDS row
    constexpr int RS  = (BK == 32) ? 1 : 0;
    constexpr int IA  = BM * BK / 2048; // global_load_lds issues per thread
    constexpr int IB  = BN * BK / 2048;
    __shared__ __align__(16) f16_t As[2][BM][BK];
    __shared__ __align__(16) f16_t Bs[2][BN][BK];

    const int tid  = threadIdx.x;
    const int wid  = tid >> 6, lane = tid & 63;
    const int wr   = wid / WC, wc = wid % WC;
    const int z    = blockIdx.z;
    const int zh   = z / zmod, zl = z % zmod;
    const f16_t* Ab = A + (long long)zh * sAhi + (long long)zl * sAlo;
    const f16_t* Bb = B + (long long)zh * sBhi + (long long)zl * sBlo;
    const int m0 = blockIdx.x * BM;
    const int n0 = blockIdx.y * BN;

    f32x4 acc[MR][NR] = {};

    // ---- staging addresses: chunk c=i*256+tid; row=c/CPR, j=c%CPR, j^=swz
    const f16_t* srcA[IA]; const f16_t* srcB[IB];
#pragma unroll
    for (int i = 0; i < IA; ++i) {
        const int c = i * 256 + tid, row = c / CPR;
        const int kch = (c % CPR) ^ ((row >> RS) & (CPR - 1));
        srcA[i] = Ab + (long long)(m0 + row) * lda + kch * 8;
    }
#pragma unroll
    for (int i = 0; i < IB; ++i) {
        const int c = i * 256 + tid, row = c / CPR;
        const int kch = (c % CPR) ^ ((row >> RS) & (CPR - 1));
        srcB[i] = Bb + (long long)(n0 + row) * ldb + kch * 8;
    }
    auto stage = [&](int bf_, int t) {
        const int k0 = t * BK;
#pragma unroll
        for (int i = 0; i < IA; ++i)
            gl_lds16(srcA[i] + k0, &As[bf_][0][0] + (i * 256 + wid * 64) * 8);
#pragma unroll
        for (int i = 0; i < IB; ++i)
            gl_lds16(srcB[i] + k0, &Bs[bf_][0][0] + (i * 256 + wid * 64) * 8);
    };

    // ---- fragment read offsets (bytes), swizzled to match staged layout
    const int l15 = lane & 15;
    const int g   = lane >> 4;
    int aoff[MR][KK], boff[NR][KK];
#pragma unroll
    for (int m = 0; m < MR; ++m) {
        const int row = wr * WMT + m * 16 + l15;
        const int swz = ((row >> RS) & (CPR - 1)) << 4;
#pragma unroll
        for (int kk = 0; kk < KK; ++kk)
            aoff[m][kk] = ((row * BK + kk * 32 + g * 8) * 2) ^ swz;
    }
#pragma unroll
    for (int n = 0; n < NR; ++n) {
        const int row = wc * WNT + n * 16 + l15;
        const int swz = ((row >> RS) & (CPR - 1)) << 4;
#pragma unroll
        for (int kk = 0; kk < KK; ++kk)
            boff[n][kk] = ((row * BK + kk * 32 + g * 8) * 2) ^ swz;
    }

    const int NT = K / BK;
    stage(0, 0);
    __syncthreads();                    // drains vmcnt before barrier

    int buf = 0;
    for (int t = 0; t < NT; ++t) {
        if (t + 1 < NT) stage(buf ^ 1, t + 1);   // loads fly during MFMA
        const char* Al = (const char*)&As[buf][0][0];
        const char* Bl = (const char*)&Bs[buf][0][0];
        f16x8 af[MR][KK], bfr[NR][KK];
#pragma unroll
        for (int m = 0; m < MR; ++m)
#pragma unroll
            for (int kk = 0; kk < KK; ++kk) af[m][kk] = *(const f16x8*)(Al + aoff[m][kk]);
#pragma unroll
        for (int n = 0; n < NR; ++n)
#pragma unroll
            for (int kk = 0; kk < KK; ++kk) bfr[n][kk] = *(const f16x8*)(Bl + boff[n][kk]);
#pragma unroll
        for (int kk = 0; kk < KK; ++kk)
#pragma unroll
            for (int m = 0; m < MR; ++m)
#pragma unroll
                for (int n = 0; n < NR; ++n)
                    acc[m][n] = __builtin_amdgcn_mfma_f32_16x16x32_f16(af[m][kk], bfr[n][kk], acc[m][n], 0, 0, 0);
        __syncthreads();                // drains vmcnt+lgkmcnt, swap safe
        buf ^= 1;
    }

    const long long cOff = (long long)zh * sChi + (long long)zl * sClo;
    const int rbase = (lane >> 4) * 4;  // C/D: row=(lane>>4)*4+r, col=lane&15
#pragma unroll
    for (int m = 0; m < MR; ++m) {
        const int row = m0 + wr * WMT + m * 16 + rbase;
#pragma unroll
        for (int n = 0; n < NR; ++n) {
            const int col = n0 + wc * WNT + n * 16 + l15;
            const float bb = bias ? bias[col] : 0.0f;
            if (VOUT && col >= 1024) {  // V head -> transposed f16x4 store
                const int hh = (col - 1024) >> 6, dv = (col - 1024) & 63;
                const int bb_ = row >> 9, t0 = row & 511;
                f16x4 v4;
#pragma unroll
                for (int r = 0; r < 4; ++r) v4[r] = (f16_t)(acc[m][n][r] + bb);
                *(f16x4*)&vt[((long long)((bb_ * 8 + hh) * 64 + dv)) * 512 + t0] = v4;
            } else {
#pragma unroll
                for (int r = 0; r < 4; ++r) {
                    float v = acc[m][n][r] + bb;
                    if (RELU) v = fmaxf(v, 0.0f);
                    const long long idx = cOff + (long long)(row + r) * ldc + col;
                    if (OUTF16) ((f16_t*)Cout)[idx] = (f16_t)v;
                    else        ((float*)Cout)[idx] = v;
                }
            }
        }
    }
}

// ------- flash attention v3 per (b,h, 64-q tile): softmax(Q K^T) V -> ao ----
// K staged in 4 double-buffered 128-key chunks (global_load_lds, coalesced;
// next chunk's loads issued before computing current). Q frags read once from
// global. LDS 40KB -> 4 blocks/CU. Per-wave P buffer; V frags from global.
__global__ void __launch_bounds__(256)
attn_flash_kernel(const f16_t* __restrict__ qkv, const f16_t* __restrict__ Vt,
                  f16_t* __restrict__ ao)
{
    __shared__ __align__(16) f16_t Ks[2][128 * 64]; // 2 x 16KB
    __shared__ __align__(16) f16_t Ps[4][16 * 64];  // 8KB (per-wave private)
    const int tid = threadIdx.x, wid = tid >> 6, lane = tid & 63;
    const int l15 = lane & 15, g = lane >> 4;
    const int z = blockIdx.y, b = z >> 3, hh = z & 7;
    const int q0 = blockIdx.x * 64;
    const f16_t* Kbase = qkv + (long long)b * 512 * 1536 + 512 + hh * 64;
    const f16_t* Qbase = qkv + (long long)(b * 512 + q0) * 1536 + hh * 64;
    const f16_t* Vbase = Vt + (long long)z * 32768;

    // stage one 128-key chunk: linear LDS dest, inverse-swizzled source
    auto stageK = [&](int bf_, int c) {
#pragma unroll
        for (int i = 0; i < 4; ++i) {
            const int ci = i * 256 + tid, t = ci >> 3, j = ci & 7;
            gl_lds16(Kbase + (long long)(c * 128 + t) * 1536 + ((j ^ (t & 7)) << 3),
                     &Ks[bf_][0] + ci * 8);
        }
    };

    // Q B-frags straight from global (one-time; latency hidden by stage wait)
    const int q = wid * 16 + l15;
    f16x8 qf[2];
#pragma unroll
    for (int k = 0; k < 2; ++k)
        qf[k] = *(const f16x8*)(Qbase + (long long)q * 1536 + k * 32 + g * 8);

    stageK(0, 0);

    f32x4 ov[4] = {};                   // O rows q=g*4+r, cols dv=n*16+l15
    float m_run = -1e30f, l_run = 0.0f;
    f16_t* Pw = &Ps[wid][0];

    __syncthreads();                    // chunk 0 staged (barrier drains vmcnt)

    int buf = 0;
    for (int c = 0; c < 4; ++c) {
        if (c + 1 < 4) stageK(buf ^ 1, c + 1);   // loads fly during compute
#pragma unroll
        for (int sub = 0; sub < 2; ++sub) {
            const int kc0 = c * 128 + sub * 64;  // global key base (V addressing)
            f16x8 vf[4][2];
#pragma unroll
            for (int n = 0; n < 4; ++n)
#pragma unroll
                for (int k = 0; k < 2; ++k)
                    vf[n][k] = *(const f16x8*)(Vbase + (n * 16 + l15) * 512 + kc0 + k * 32 + g * 8);
            // S^T = K_chunk . Q^T : rows=keys, cols=q
            f32x4 s[4] = {};
            __builtin_amdgcn_s_setprio(1);
#pragma unroll
            for (int k = 0; k < 2; ++k)
#pragma unroll
                for (int m = 0; m < 4; ++m) {
                    const int lr = sub * 64 + m * 16 + l15;   // local key row
                    const f16x8 a = *(const f16x8*)(&Ks[buf][0] + lr * 64 +
                                       (((k * 4 + g) ^ (lr & 7)) << 3));
                    s[m] = __builtin_amdgcn_mfma_f32_16x16x32_f16(a, qf[k], s[m], 0, 0, 0);
                }
            __builtin_amdgcn_s_setprio(0);
            // online softmax over keys for q = l15
            float cmax = -1e30f;
#pragma unroll
            for (int m = 0; m < 4; ++m)
#pragma unroll
                for (int r = 0; r < 4; ++r) cmax = fmaxf(cmax, s[m][r]);
            cmax = fmaxf(cmax, __shfl_xor(cmax, 16, 64));
            cmax = fmaxf(cmax, __shfl_xor(cmax, 32, 64));
            const float mnew = fmaxf(m_run, cmax);
            const float corr = __expf(m_run - mnew);
            float csum = 0.0f;
#pragma unroll
            for (int m = 0; m < 4; ++m) {
                f16x4 p4;
#pragma unroll
                for (int r = 0; r < 4; ++r) {
                    const float pe = __expf(s[m][r] - mnew);
                    csum += pe;
                    p4[r] = (f16_t)pe;
                }
                *(f16x4*)(Pw + l15 * 64 + ((((m * 2 + (g >> 1)) ^ (l15 & 7))) << 3) + ((g & 1) << 2)) = p4;
            }
            csum += __shfl_xor(csum, 16, 64);
            csum += __shfl_xor(csum, 32, 64);
            l_run = l_run * corr + csum;
            m_run = mnew;
            float cr[4];
#pragma unroll
            for (int r = 0; r < 4; ++r) cr[r] = __shfl(corr, g * 4 + r, 64);
#pragma unroll
            for (int n = 0; n < 4; ++n)
#pragma unroll
                for (int r = 0; r < 4; ++r) ov[n][r] *= cr[r];
#pragma unroll
            for (int k = 0; k < 2; ++k) {
                const f16x8 pf = *(const f16x8*)(Pw + l15 * 64 + (((k * 4 + g) ^ (l15 & 7)) << 3));
                __builtin_amdgcn_s_setprio(1);
#pragma unroll
                for (int n = 0; n < 4; ++n)
                    ov[n] = __builtin_amdgcn_mfma_f32_16x16x32_f16(pf, vf[n][k], ov[n], 0, 0, 0);
                __builtin_amdgcn_s_setprio(0);
            }
        }
        __syncthreads();                // next chunk staged; buf swap safe
        buf ^= 1;
    }

    const float inv = 1.0f / l_run;
    float ir[4];
#pragma unroll
    for (int r = 0; r < 4; ++r) ir[r] = __shfl(inv, g * 4 + r, 64);
#pragma unroll
    for (int n = 0; n < 4; ++n)
#pragma unroll
        for (int r = 0; r < 4; ++r) {
            const long long row = b * 512 + q0 + wid * 16 + g * 4 + r;
            ao[row * 512 + hh * 64 + n * 16 + l15] = (f16_t)(ov[n][r] * ir[r]);
        }
}

// ---- fused setup: wconv 64x64 (4608 blks) + embed (4096) + biascat (36) ----
__global__ void __launch_bounds__(256)
setup_kernel(const float* __restrict__ Wq, const float* __restrict__ Wk,
             const float* __restrict__ Wv, const float* __restrict__ Wo,
             const float* __restrict__ W1, const float* __restrict__ W2,
             f16_t* __restrict__ wT,
             const int* __restrict__ xt, const float* __restrict__ emb,
             f16_t* __restrict__ hb,
             const float* __restrict__ bq, const float* __restrict__ bk,
             const float* __restrict__ bv, float* __restrict__ qkvb)
{
    __shared__ float tile[64][65];
    const int blk = blockIdx.x;
    const int tid = threadIdx.x;
    if (blk < 4608) {                   // ---- weight convert+transpose 64x64
        const int layer = blk / 768;
        const int r     = blk % 768;
        const float* src; f16_t* dst; int R, C, tt;
        if (r < 256) {                  // Wq,Wk,Wv,Wo: [512,512], 64 tiles each
            const int mat = r >> 6; tt = r & 63; R = 512; C = 512;
            const float* s4 = (mat == 0) ? Wq : (mat == 1) ? Wk : (mat == 2) ? Wv : Wo;
            src = s4 + (long long)layer * 262144;
            dst = wT + (long long)layer * LSTR + (long long)mat * 262144;
        } else if (r < 512) {           // W1: [512,2048]
            tt = r - 256; R = 512; C = 2048;
            src = W1 + (long long)layer * 1048576;
            dst = wT + (long long)layer * LSTR + 1048576;
        } else {                        // W2: [2048,512]
            tt = r - 512; R = 2048; C = 512;
            src = W2 + (long long)layer * 1048576;
            dst = wT + (long long)layer * LSTR + 2097152;
        }
        const int tC = C >> 6;
        const int tr = tt / tC, tc = tt % tC;
        const int r0 = tr * 64, c0 = tc * 64;
        const int tx = tid & 15, ty = tid >> 4;
#pragma unroll
        for (int i = 0; i < 4; ++i)
            *(float4*)&tile[ty + 16 * i][tx * 4] =
                *(const float4*)&src[(long long)(r0 + ty + 16 * i) * C + c0 + tx * 4];
        __syncthreads();
#pragma unroll
        for (int i = 0; i < 4; ++i) {
            f16x4 o;
#pragma unroll
            for (int e = 0; e < 4; ++e) o[e] = (f16_t)tile[tx * 4 + e][ty + 16 * i];
            *(f16x4*)&dst[(long long)(c0 + ty + 16 * i) * R + r0 + tx * 4] = o;
        }
    } else if (blk < 4608 + 4096) {     // ---- embedding + sinusoidal PE
        const int row = blk - 4608;
        const int t   = row & 511;
        const int tok = xt[row];
#pragma unroll
        for (int s = 0; s < 2; ++s) {
            const int d = tid + s * 256;
            const int i = d >> 1;
            const float inv = expf((float)(2 * i) * (-9.210340371976184f / 512.0f));
            const float ang = (float)t * inv;
            const float pe  = (d & 1) ? cosf(ang) : sinf(ang);
            hb[(long long)row * 512 + d] = (f16_t)(emb[(long long)tok * 512 + d] + pe);
        }
    } else {                            // ---- bias concat
        const int i = (blk - 8704) * 256 + tid;
        if (i < 9216) {
            const int l = i / 1536, c = i % 1536;
            float v;
            if (c < 512)       v = bq[l * 512 + c];
            else if (c < 1024) v = bk[l * 512 + c - 512];
            else               v = bv[l * 512 + c - 1024];
            qkvb[i] = v;
        }
    }
}

// ---- hb = LN( sum_{s<ns} X[s] + bias + hb ); wave-per-row, no barriers -----
__global__ void __launch_bounds__(256)
add_ln_kernel(const f16_t* __restrict__ X, int ns, long long sstr,
              const float* __restrict__ bias,
              const float* __restrict__ g, const float* __restrict__ b,
              f16_t* __restrict__ Hf)
{
    const int wid = threadIdx.x >> 6, lane = threadIdx.x & 63;
    const long long row = (long long)blockIdx.x * 4 + wid;
    f16_t* h = Hf + row * 512;
    const int c0 = lane * 8;
    const f16x8 hv = *(const f16x8*)&h[c0];
    float v[8];
#pragma unroll
    for (int e = 0; e < 8; ++e) v[e] = (float)hv[e] + bias[c0 + e];
    for (int s = 0; s < ns; ++s) {
        const f16x8 xv = *(const f16x8*)&X[s * sstr + row * 512 + c0];
#pragma unroll
        for (int e = 0; e < 8; ++e) v[e] += (float)xv[e];
    }
    float sum = 0.0f, sq = 0.0f;
#pragma unroll
    for (int e = 0; e < 8; ++e) { sum += v[e]; sq += v[e] * v[e]; }
#pragma unroll
    for (int o = 1; o < 64; o <<= 1) {
        sum += __shfl_xor(sum, o, 64);
        sq  += __shfl_xor(sq,  o, 64);
    }
    const float mu = sum * (1.0f / 512.0f);
    float var = sq * (1.0f / 512.0f) - mu * mu;
    var = fmaxf(var, 0.0f);
    const float rs = rsqrtf(var + 1e-5f);
    f16x8 o8;
#pragma unroll
    for (int e = 0; e < 8; ++e)
        o8[e] = (f16_t)(g[c0 + e] * (v[e] - mu) * rs + b[c0 + e]);
    *(f16x8*)&h[c0] = o8;
}

// ---------------- classifier head: split reduction (hb f16) -----------------
__global__ void head_partial_kernel(const f16_t* __restrict__ hb, const float* __restrict__ Wout,
                                    float* __restrict__ partials)
{
    const int blk = blockIdx.x;         // 8 b * 64 chunks
    const int b = blk >> 6, chunk = blk & 63;
    const int tid = threadIdx.x;
    const f16_t* hp = hb + (long long)b * 262144 + (long long)chunk * 4096;
    float a0 = 0, a1 = 0, a2 = 0, a3 = 0, a4 = 0;
    for (int it = 0; it < 16; ++it) {
        const int idx = it * 256 + tid;
        const float hv = (float)hp[idx];
        const float* w = Wout + ((long long)chunk * 4096 + idx) * 5;
        a0 += hv * w[0]; a1 += hv * w[1]; a2 += hv * w[2]; a3 += hv * w[3]; a4 += hv * w[4];
    }
#pragma unroll
    for (int o = 32; o > 0; o >>= 1) {
        a0 += __shfl_down(a0, o, 64); a1 += __shfl_down(a1, o, 64); a2 += __shfl_down(a2, o, 64);
        a3 += __shfl_down(a3, o, 64); a4 += __shfl_down(a4, o, 64);
    }
    __shared__ float sm[4][5];
    const int lane = tid & 63, w = tid >> 6;
    if (lane == 0) { sm[w][0] = a0; sm[w][1] = a1; sm[w][2] = a2; sm[w][3] = a3; sm[w][4] = a4; }
    __syncthreads();
    if (tid < 5)
        partials[(long long)blk * 5 + tid] = sm[0][tid] + sm[1][tid] + sm[2][tid] + sm[3][tid];
}

__global__ void head_final_kernel(const float* __restrict__ partials, const float* __restrict__ bout,
                                  float* __restrict__ out)
{
    const int tid = threadIdx.x;
    if (tid >= 40) return;
    const int b = tid / 5, c = tid % 5;
    float s = bout[c];
    const float* p = partials + (long long)b * 64 * 5 + c;
    for (int ck = 0; ck < 64; ++ck) s += p[ck * 5];
    out[tid] = s;   // reference output dtype is float32
}

// ---------------------------------------------------------------------------
extern "C" void kernel_launch(void* const* d_in, const int* in_sizes, int n_in,
                              void* d_out, int out_size, void* d_ws, size_t ws_size,
                              hipStream_t stream)
{
    (void)in_sizes; (void)n_in; (void)out_size; (void)ws_size;
    const int*   x_tok = (const int*)  d_in[0];
    const float* emb   = (const float*)d_in[2];
    const float* Wq    = (const float*)d_in[3];
    const float* bq    = (const float*)d_in[4];
    const float* Wk    = (const float*)d_in[5];
    const float* bk    = (const float*)d_in[6];
    const float* Wv    = (const float*)d_in[7];
    const float* bv    = (const float*)d_in[8];
    const float* Wo    = (const float*)d_in[9];
    const float* bo    = (const float*)d_in[10];
    const float* gma   = (const float*)d_in[11];
    const float* bta   = (const float*)d_in[12];
    const float* W1    = (const float*)d_in[13];
    const float* b1    = (const float*)d_in[14];
    const float* W2    = (const float*)d_in[15];
    const float* b2    = (const float*)d_in[16];
    const float* Wout  = (const float*)d_in[17];
    const float* bout  = (const float*)d_in[18];

    char* ws = (char*)d_ws;
    size_t off = 0;
    auto take = [&](size_t bytes) { char* p = ws + off; off += (bytes + 255) & ~(size_t)255; return p; };
    f16_t* wT    = (f16_t*)take(18874368ULL * 2);  // transposed f16 weights
    f16_t* hb    = (f16_t*)take(2097152ULL * 2);   // residual stream (f16)
    f16_t* qkv   = (f16_t*)take(6291456ULL * 2);   // [4096][1536] (Q,K used)
    f16_t* Vt    = (f16_t*)take(2097152ULL * 2);   // [64][64][512]
    f16_t* ao    = (f16_t*)take(2097152ULL * 2);   // attn out [4096][512]
    f16_t* f1    = (f16_t*)take(8388608ULL * 2);   // ffn hidden [4096][2048]
    f16_t* t16   = (f16_t*)take(4ULL * 2097152ULL * 2); // split-K f16 partials
    float* qkvb  = (float*)take(9216ULL * 4);
    float* parts = (float*)take(2560ULL * 4);

    setup_kernel<<<dim3(8740), 256, 0, stream>>>(Wq, Wk, Wv, Wo, W1, W2, wT,
                                                 x_tok, emb, hb, bq, bk, bv, qkvb);

    for (int l = 0; l < 6; ++l) {
        const f16_t* wl = wT + (long long)l * LSTR;
        // QKV: [4096,512]@[512,1536]; V heads written transposed to Vt
        gemm_kernel<64,128,64,2,2,1,0,1><<<dim3(64,12,1),256,0,stream>>>(hb, wl, qkvb + l*1536,
            qkv, Vt, 4096,1536,512, 512,512,1536, 1, 0,0,0,0,0,0);
        // flash attention v3: softmax(QK^T)V -> ao
        attn_flash_kernel<<<dim3(8,64),256,0,stream>>>(qkv, Vt, ao);
        // O proj: 64x128 split-K x2 (512 blocks) -> t16 slices
        gemm_kernel<64,128,64,2,2,1,0,0><<<dim3(64,4,2),256,0,stream>>>(ao, wl + 786432, nullptr,
            t16, nullptr, 4096,512,256, 512,512,512, 1, 256LL,0LL, 256LL,0LL, 2097152LL,0LL);
        add_ln_kernel<<<dim3(1024),256,0,stream>>>(t16, 2, 2097152LL, bo + l*512,
            gma + l*512, bta + l*512, hb);
        // FFN1 + relu -> f1 f16: 128x128/BK=32 (512 blocks, 2/CU uniform)
        gemm_kernel<128,128,32,2,2,1,1,0><<<dim3(32,16,1),256,0,stream>>>(hb, wl + 1048576, b1 + l*2048,
            f1, nullptr, 4096,2048,512, 512,512,2048, 1, 0,0,0,0,0,0);
        // FFN2: 128x128/BK=32 split-K x4 (512 blocks, 2/CU) -> t16 slices
        gemm_kernel<128,128,32,2,2,1,0,0><<<dim3(32,4,4),256,0,stream>>>(f1, wl + 2097152, nullptr,
            t16, nullptr, 4096,512,512, 2048,2048,512, 1, 512LL,0LL, 512LL,0LL, 2097152LL,0LL);
        add_ln_kernel<<<dim3(1024),256,0,stream>>>(t16, 4, 2097152LL, b2 + l*512,
            gma + l*512, bta + l*512, hb);
    }

    head_partial_kernel<<<dim3(512),256,0,stream>>>(hb, Wout, parts);
    head_final_kernel  <<<dim3(1),64,0,stream>>>(parts, bout, (float*)d_out);
}

// Round 13
// 530.399 us; speedup vs baseline: 1.2261x; 1.0515x over previous
//
#include <hip/hip_runtime.h>
#include <hip/hip_bf16.h>

// ---------------------------------------------------------------------------
// 6-layer transformer forward, MI355X. f16 MFMA compute, f32 stats.
// Round 13: FFN1/FFN2 to 128x128/BK=64 (half the barrier drains; LDS 64KB
//           but grids are 2/CU grid-limited so occupancy unchanged).
// ---------------------------------------------------------------------------

typedef _Float16 f16_t;
typedef _Float16 f16x8 __attribute__((ext_vector_type(8)));
typedef _Float16 f16x4 __attribute__((ext_vector_type(4)));
typedef _Float16 f16x2 __attribute__((ext_vector_type(2)));
typedef float    f32x4 __attribute__((ext_vector_type(4)));

#define LSTR 3145728LL  // per-layer transposed-weight stride (f16 elems)

__device__ __forceinline__ void gl_lds16(const f16_t* g, f16_t* l) {
    __builtin_amdgcn_global_load_lds(
        (const __attribute__((address_space(1))) unsigned int*)g,
        (__attribute__((address_space(3))) unsigned int*)l, 16, 0, 0);
}

// ---------------- pipelined batched GEMM: C = A[M,K] * (Bt[N,K])^T + bias ---
// A, Bt f16 row-major. blockIdx.z -> zh=z/zmod, zl=z%zmod; per-operand strides.
// Split-K via zmod=1: sAhi/sBhi = K-slice offset, sChi = C-slice stride.
// LDS: linear dest (global_load_lds), XOR-swizzled 16B k-chunk on BOTH the
// global source and the LDS read offset (rule #21). BK=64: swz=row&7;
// BK=32: swz=(row>>1)&3.
// VOUT=1 (QKV): cols>=1024 are V heads -> written transposed to vt
// ([b*8+h][64][512]) as f16x4 (4 consecutive t per fragment); qkv gets Q,K.
template<int BM, int BN, int BK, int WR, int WC, int OUTF16, int RELU, int VOUT>
__global__ void __launch_bounds__(256)
gemm_kernel(const f16_t* __restrict__ A, const f16_t* __restrict__ B,
            const float* __restrict__ bias, void* __restrict__ Cout,
            f16_t* __restrict__ vt,
            int M, int N, int K, int lda, int ldb, int ldc, int zmod,
            long long sAhi, long long sAlo, long long sBhi, long long sBlo,
            long long sChi, long long sClo)
{
    constexpr int WMT = BM / WR;
    constexpr int WNT = BN / WC;
    constexpr int MR  = WMT / 16;
    constexpr int NR  = WNT / 16;
    constexpr int KK  = BK / 32;        // 16x16x32 MFMA k-substeps per K-step
    constexpr int CPR = BK / 8;         // 16B chunks per LDS row
    constexpr int RS  = (BK == 32) ? 1 : 0;
    constexpr int IA  = BM * BK / 2048; // global_load_lds issues per thread
    constexpr int IB  = BN * BK / 2048;
    __shared__ __align__(16) f16_t As[2][BM][BK];
    __shared__ __align__(16) f16_t Bs[2][BN][BK];

    const int tid  = threadIdx.x;
    const int wid  = tid >> 6, lane = tid & 63;
    const int wr   = wid / WC, wc = wid % WC;
    const int z    = blockIdx.z;
    const int zh   = z / zmod, zl = z % zmod;
    const f16_t* Ab = A + (long long)zh * sAhi + (long long)zl * sAlo;
    const f16_t* Bb = B + (long long)zh * sBhi + (long long)zl * sBlo;
    const int m0 = blockIdx.x * BM;
    const int n0 = blockIdx.y * BN;

    f32x4 acc[MR][NR] = {};

    // ---- staging addresses: chunk c=i*256+tid; row=c/CPR, j=c%CPR, j^=swz
    const f16_t* srcA[IA]; const f16_t* srcB[IB];
#pragma unroll
    for (int i = 0; i < IA; ++i) {
        const int c = i * 256 + tid, row = c / CPR;
        const int kch = (c % CPR) ^ ((row >> RS) & (CPR - 1));
        srcA[i] = Ab + (long long)(m0 + row) * lda + kch * 8;
    }
#pragma unroll
    for (int i = 0; i < IB; ++i) {
        const int c = i * 256 + tid, row = c / CPR;
        const int kch = (c % CPR) ^ ((row >> RS) & (CPR - 1));
        srcB[i] = Bb + (long long)(n0 + row) * ldb + kch * 8;
    }
    auto stage = [&](int bf_, int t) {
        const int k0 = t * BK;
#pragma unroll
        for (int i = 0; i < IA; ++i)
            gl_lds16(srcA[i] + k0, &As[bf_][0][0] + (i * 256 + wid * 64) * 8);
#pragma unroll
        for (int i = 0; i < IB; ++i)
            gl_lds16(srcB[i] + k0, &Bs[bf_][0][0] + (i * 256 + wid * 64) * 8);
    };

    // ---- fragment read offsets (bytes), swizzled to match staged layout
    const int l15 = lane & 15;
    const int g   = lane >> 4;
    int aoff[MR][KK], boff[NR][KK];
#pragma unroll
    for (int m = 0; m < MR; ++m) {
        const int row = wr * WMT + m * 16 + l15;
        const int swz = ((row >> RS) & (CPR - 1)) << 4;
#pragma unroll
        for (int kk = 0; kk < KK; ++kk)
            aoff[m][kk] = ((row * BK + kk * 32 + g * 8) * 2) ^ swz;
    }
#pragma unroll
    for (int n = 0; n < NR; ++n) {
        const int row = wc * WNT + n * 16 + l15;
        const int swz = ((row >> RS) & (CPR - 1)) << 4;
#pragma unroll
        for (int kk = 0; kk < KK; ++kk)
            boff[n][kk] = ((row * BK + kk * 32 + g * 8) * 2) ^ swz;
    }

    const int NT = K / BK;
    stage(0, 0);
    __syncthreads();                    // drains vmcnt before barrier

    int buf = 0;
    for (int t = 0; t < NT; ++t) {
        if (t + 1 < NT) stage(buf ^ 1, t + 1);   // loads fly during MFMA
        const char* Al = (const char*)&As[buf][0][0];
        const char* Bl = (const char*)&Bs[buf][0][0];
        f16x8 af[MR][KK], bfr[NR][KK];
#pragma unroll
        for (int m = 0; m < MR; ++m)
#pragma unroll
            for (int kk = 0; kk < KK; ++kk) af[m][kk] = *(const f16x8*)(Al + aoff[m][kk]);
#pragma unroll
        for (int n = 0; n < NR; ++n)
#pragma unroll
            for (int kk = 0; kk < KK; ++kk) bfr[n][kk] = *(const f16x8*)(Bl + boff[n][kk]);
#pragma unroll
        for (int kk = 0; kk < KK; ++kk)
#pragma unroll
            for (int m = 0; m < MR; ++m)
#pragma unroll
                for (int n = 0; n < NR; ++n)
                    acc[m][n] = __builtin_amdgcn_mfma_f32_16x16x32_f16(af[m][kk], bfr[n][kk], acc[m][n], 0, 0, 0);
        __syncthreads();                // drains vmcnt+lgkmcnt, swap safe
        buf ^= 1;
    }

    const long long cOff = (long long)zh * sChi + (long long)zl * sClo;
    const int rbase = (lane >> 4) * 4;  // C/D: row=(lane>>4)*4+r, col=lane&15
#pragma unroll
    for (int m = 0; m < MR; ++m) {
        const int row = m0 + wr * WMT + m * 16 + rbase;
#pragma unroll
        for (int n = 0; n < NR; ++n) {
            const int col = n0 + wc * WNT + n * 16 + l15;
            const float bb = bias ? bias[col] : 0.0f;
            if (VOUT && col >= 1024) {  // V head -> transposed f16x4 store
                const int hh = (col - 1024) >> 6, dv = (col - 1024) & 63;
                const int bb_ = row >> 9, t0 = row & 511;
                f16x4 v4;
#pragma unroll
                for (int r = 0; r < 4; ++r) v4[r] = (f16_t)(acc[m][n][r] + bb);
                *(f16x4*)&vt[((long long)((bb_ * 8 + hh) * 64 + dv)) * 512 + t0] = v4;
            } else {
#pragma unroll
                for (int r = 0; r < 4; ++r) {
                    float v = acc[m][n][r] + bb;
                    if (RELU) v = fmaxf(v, 0.0f);
                    const long long idx = cOff + (long long)(row + r) * ldc + col;
                    if (OUTF16) ((f16_t*)Cout)[idx] = (f16_t)v;
                    else        ((float*)Cout)[idx] = v;
                }
            }
        }
    }
}

// ------- flash attention v3 per (b,h, 64-q tile): softmax(Q K^T) V -> ao ----
// K staged in 4 double-buffered 128-key chunks (global_load_lds, coalesced;
// next chunk's loads issued before computing current). Q frags read once from
// global. LDS 40KB -> 4 blocks/CU. Per-wave P buffer; V frags from global.
__global__ void __launch_bounds__(256)
attn_flash_kernel(const f16_t* __restrict__ qkv, const f16_t* __restrict__ Vt,
                  f16_t* __restrict__ ao)
{
    __shared__ __align__(16) f16_t Ks[2][128 * 64]; // 2 x 16KB
    __shared__ __align__(16) f16_t Ps[4][16 * 64];  // 8KB (per-wave private)
    const int tid = threadIdx.x, wid = tid >> 6, lane = tid & 63;
    const int l15 = lane & 15, g = lane >> 4;
    const int z = blockIdx.y, b = z >> 3, hh = z & 7;
    const int q0 = blockIdx.x * 64;
    const f16_t* Kbase = qkv + (long long)b * 512 * 1536 + 512 + hh * 64;
    const f16_t* Qbase = qkv + (long long)(b * 512 + q0) * 1536 + hh * 64;
    const f16_t* Vbase = Vt + (long long)z * 32768;

    // stage one 128-key chunk: linear LDS dest, inverse-swizzled source
    auto stageK = [&](int bf_, int c) {
#pragma unroll
        for (int i = 0; i < 4; ++i) {
            const int ci = i * 256 + tid, t = ci >> 3, j = ci & 7;
            gl_lds16(Kbase + (long long)(c * 128 + t) * 1536 + ((j ^ (t & 7)) << 3),
                     &Ks[bf_][0] + ci * 8);
        }
    };

    // Q B-frags straight from global (one-time; latency hidden by stage wait)
    const int q = wid * 16 + l15;
    f16x8 qf[2];
#pragma unroll
    for (int k = 0; k < 2; ++k)
        qf[k] = *(const f16x8*)(Qbase + (long long)q * 1536 + k * 32 + g * 8);

    stageK(0, 0);

    f32x4 ov[4] = {};                   // O rows q=g*4+r, cols dv=n*16+l15
    float m_run = -1e30f, l_run = 0.0f;
    f16_t* Pw = &Ps[wid][0];

    __syncthreads();                    // chunk 0 staged (barrier drains vmcnt)

    int buf = 0;
    for (int c = 0; c < 4; ++c) {
        if (c + 1 < 4) stageK(buf ^ 1, c + 1);   // loads fly during compute
#pragma unroll
        for (int sub = 0; sub < 2; ++sub) {
            const int kc0 = c * 128 + sub * 64;  // global key base (V addressing)
            f16x8 vf[4][2];
#pragma unroll
            for (int n = 0; n < 4; ++n)
#pragma unroll
                for (int k = 0; k < 2; ++k)
                    vf[n][k] = *(const f16x8*)(Vbase + (n * 16 + l15) * 512 + kc0 + k * 32 + g * 8);
            // S^T = K_chunk . Q^T : rows=keys, cols=q
            f32x4 s[4] = {};
            __builtin_amdgcn_s_setprio(1);
#pragma unroll
            for (int k = 0; k < 2; ++k)
#pragma unroll
                for (int m = 0; m < 4; ++m) {
                    const int lr = sub * 64 + m * 16 + l15;   // local key row
                    const f16x8 a = *(const f16x8*)(&Ks[buf][0] + lr * 64 +
                                       (((k * 4 + g) ^ (lr & 7)) << 3));
                    s[m] = __builtin_amdgcn_mfma_f32_16x16x32_f16(a, qf[k], s[m], 0, 0, 0);
                }
            __builtin_amdgcn_s_setprio(0);
            // online softmax over keys for q = l15
            float cmax = -1e30f;
#pragma unroll
            for (int m = 0; m < 4; ++m)
#pragma unroll
                for (int r = 0; r < 4; ++r) cmax = fmaxf(cmax, s[m][r]);
            cmax = fmaxf(cmax, __shfl_xor(cmax, 16, 64));
            cmax = fmaxf(cmax, __shfl_xor(cmax, 32, 64));
            const float mnew = fmaxf(m_run, cmax);
            const float corr = __expf(m_run - mnew);
            float csum = 0.0f;
#pragma unroll
            for (int m = 0; m < 4; ++m) {
                f16x4 p4;
#pragma unroll
                for (int r = 0; r < 4; ++r) {
                    const float pe = __expf(s[m][r] - mnew);
                    csum += pe;
                    p4[r] = (f16_t)pe;
                }
                *(f16x4*)(Pw + l15 * 64 + ((((m * 2 + (g >> 1)) ^ (l15 & 7))) << 3) + ((g & 1) << 2)) = p4;
            }
            csum += __shfl_xor(csum, 16, 64);
            csum += __shfl_xor(csum, 32, 64);
            l_run = l_run * corr + csum;
            m_run = mnew;
            float cr[4];
#pragma unroll
            for (int r = 0; r < 4; ++r) cr[r] = __shfl(corr, g * 4 + r, 64);
#pragma unroll
            for (int n = 0; n < 4; ++n)
#pragma unroll
                for (int r = 0; r < 4; ++r) ov[n][r] *= cr[r];
#pragma unroll
            for (int k = 0; k < 2; ++k) {
                const f16x8 pf = *(const f16x8*)(Pw + l15 * 64 + (((k * 4 + g) ^ (l15 & 7)) << 3));
                __builtin_amdgcn_s_setprio(1);
#pragma unroll
                for (int n = 0; n < 4; ++n)
                    ov[n] = __builtin_amdgcn_mfma_f32_16x16x32_f16(pf, vf[n][k], ov[n], 0, 0, 0);
                __builtin_amdgcn_s_setprio(0);
            }
        }
        __syncthreads();                // next chunk staged; buf swap safe
        buf ^= 1;
    }

    const float inv = 1.0f / l_run;
    float ir[4];
#pragma unroll
    for (int r = 0; r < 4; ++r) ir[r] = __shfl(inv, g * 4 + r, 64);
#pragma unroll
    for (int n = 0; n < 4; ++n)
#pragma unroll
        for (int r = 0; r < 4; ++r) {
            const long long row = b * 512 + q0 + wid * 16 + g * 4 + r;
            ao[row * 512 + hh * 64 + n * 16 + l15] = (f16_t)(ov[n][r] * ir[r]);
        }
}

// ---- fused setup: wconv 64x64 (4608 blks) + embed (4096) + biascat (36) ----
__global__ void __launch_bounds__(256)
setup_kernel(const float* __restrict__ Wq, const float* __restrict__ Wk,
             const float* __restrict__ Wv, const float* __restrict__ Wo,
             const float* __restrict__ W1, const float* __restrict__ W2,
             f16_t* __restrict__ wT,
             const int* __restrict__ xt, const float* __restrict__ emb,
             f16_t* __restrict__ hb,
             const float* __restrict__ bq, const float* __restrict__ bk,
             const float* __restrict__ bv, float* __restrict__ qkvb)
{
    __shared__ float tile[64][65];
    const int blk = blockIdx.x;
    const int tid = threadIdx.x;
    if (blk < 4608) {                   // ---- weight convert+transpose 64x64
        const int layer = blk / 768;
        const int r     = blk % 768;
        const float* src; f16_t* dst; int R, C, tt;
        if (r < 256) {                  // Wq,Wk,Wv,Wo: [512,512], 64 tiles each
            const int mat = r >> 6; tt = r & 63; R = 512; C = 512;
            const float* s4 = (mat == 0) ? Wq : (mat == 1) ? Wk : (mat == 2) ? Wv : Wo;
            src = s4 + (long long)layer * 262144;
            dst = wT + (long long)layer * LSTR + (long long)mat * 262144;
        } else if (r < 512) {           // W1: [512,2048]
            tt = r - 256; R = 512; C = 2048;
            src = W1 + (long long)layer * 1048576;
            dst = wT + (long long)layer * LSTR + 1048576;
        } else {                        // W2: [2048,512]
            tt = r - 512; R = 2048; C = 512;
            src = W2 + (long long)layer * 1048576;
            dst = wT + (long long)layer * LSTR + 2097152;
        }
        const int tC = C >> 6;
        const int tr = tt / tC, tc = tt % tC;
        const int r0 = tr * 64, c0 = tc * 64;
        const int tx = tid & 15, ty = tid >> 4;
#pragma unroll
        for (int i = 0; i < 4; ++i)
            *(float4*)&tile[ty + 16 * i][tx * 4] =
                *(const float4*)&src[(long long)(r0 + ty + 16 * i) * C + c0 + tx * 4];
        __syncthreads();
#pragma unroll
        for (int i = 0; i < 4; ++i) {
            f16x4 o;
#pragma unroll
            for (int e = 0; e < 4; ++e) o[e] = (f16_t)tile[tx * 4 + e][ty + 16 * i];
            *(f16x4*)&dst[(long long)(c0 + ty + 16 * i) * R + r0 + tx * 4] = o;
        }
    } else if (blk < 4608 + 4096) {     // ---- embedding + sinusoidal PE
        const int row = blk - 4608;
        const int t   = row & 511;
        const int tok = xt[row];
#pragma unroll
        for (int s = 0; s < 2; ++s) {
            const int d = tid + s * 256;
            const int i = d >> 1;
            const float inv = expf((float)(2 * i) * (-9.210340371976184f / 512.0f));
            const float ang = (float)t * inv;
            const float pe  = (d & 1) ? cosf(ang) : sinf(ang);
            hb[(long long)row * 512 + d] = (f16_t)(emb[(long long)tok * 512 + d] + pe);
        }
    } else {                            // ---- bias concat
        const int i = (blk - 8704) * 256 + tid;
        if (i < 9216) {
            const int l = i / 1536, c = i % 1536;
            float v;
            if (c < 512)       v = bq[l * 512 + c];
            else if (c < 1024) v = bk[l * 512 + c - 512];
            else               v = bv[l * 512 + c - 1024];
            qkvb[i] = v;
        }
    }
}

// ---- hb = LN( sum_{s<ns} X[s] + bias + hb ); wave-per-row, no barriers -----
__global__ void __launch_bounds__(256)
add_ln_kernel(const f16_t* __restrict__ X, int ns, long long sstr,
              const float* __restrict__ bias,
              const float* __restrict__ g, const float* __restrict__ b,
              f16_t* __restrict__ Hf)
{
    const int wid = threadIdx.x >> 6, lane = threadIdx.x & 63;
    const long long row = (long long)blockIdx.x * 4 + wid;
    f16_t* h = Hf + row * 512;
    const int c0 = lane * 8;
    const f16x8 hv = *(const f16x8*)&h[c0];
    float v[8];
#pragma unroll
    for (int e = 0; e < 8; ++e) v[e] = (float)hv[e] + bias[c0 + e];
    for (int s = 0; s < ns; ++s) {
        const f16x8 xv = *(const f16x8*)&X[s * sstr + row * 512 + c0];
#pragma unroll
        for (int e = 0; e < 8; ++e) v[e] += (float)xv[e];
    }
    float sum = 0.0f, sq = 0.0f;
#pragma unroll
    for (int e = 0; e < 8; ++e) { sum += v[e]; sq += v[e] * v[e]; }
#pragma unroll
    for (int o = 1; o < 64; o <<= 1) {
        sum += __shfl_xor(sum, o, 64);
        sq  += __shfl_xor(sq,  o, 64);
    }
    const float mu = sum * (1.0f / 512.0f);
    float var = sq * (1.0f / 512.0f) - mu * mu;
    var = fmaxf(var, 0.0f);
    const float rs = rsqrtf(var + 1e-5f);
    f16x8 o8;
#pragma unroll
    for (int e = 0; e < 8; ++e)
        o8[e] = (f16_t)(g[c0 + e] * (v[e] - mu) * rs + b[c0 + e]);
    *(f16x8*)&h[c0] = o8;
}

// ---------------- classifier head: split reduction (hb f16) -----------------
__global__ void head_partial_kernel(const f16_t* __restrict__ hb, const float* __restrict__ Wout,
                                    float* __restrict__ partials)
{
    const int blk = blockIdx.x;         // 8 b * 64 chunks
    const int b = blk >> 6, chunk = blk & 63;
    const int tid = threadIdx.x;
    const f16_t* hp = hb + (long long)b * 262144 + (long long)chunk * 4096;
    float a0 = 0, a1 = 0, a2 = 0, a3 = 0, a4 = 0;
    for (int it = 0; it < 16; ++it) {
        const int idx = it * 256 + tid;
        const float hv = (float)hp[idx];
        const float* w = Wout + ((long long)chunk * 4096 + idx) * 5;
        a0 += hv * w[0]; a1 += hv * w[1]; a2 += hv * w[2]; a3 += hv * w[3]; a4 += hv * w[4];
    }
#pragma unroll
    for (int o = 32; o > 0; o >>= 1) {
        a0 += __shfl_down(a0, o, 64); a1 += __shfl_down(a1, o, 64); a2 += __shfl_down(a2, o, 64);
        a3 += __shfl_down(a3, o, 64); a4 += __shfl_down(a4, o, 64);
    }
    __shared__ float sm[4][5];
    const int lane = tid & 63, w = tid >> 6;
    if (lane == 0) { sm[w][0] = a0; sm[w][1] = a1; sm[w][2] = a2; sm[w][3] = a3; sm[w][4] = a4; }
    __syncthreads();
    if (tid < 5)
        partials[(long long)blk * 5 + tid] = sm[0][tid] + sm[1][tid] + sm[2][tid] + sm[3][tid];
}

__global__ void head_final_kernel(const float* __restrict__ partials, const float* __restrict__ bout,
                                  float* __restrict__ out)
{
    const int tid = threadIdx.x;
    if (tid >= 40) return;
    const int b = tid / 5, c = tid % 5;
    float s = bout[c];
    const float* p = partials + (long long)b * 64 * 5 + c;
    for (int ck = 0; ck < 64; ++ck) s += p[ck * 5];
    out[tid] = s;   // reference output dtype is float32
}

// ---------------------------------------------------------------------------
extern "C" void kernel_launch(void* const* d_in, const int* in_sizes, int n_in,
                              void* d_out, int out_size, void* d_ws, size_t ws_size,
                              hipStream_t stream)
{
    (void)in_sizes; (void)n_in; (void)out_size; (void)ws_size;
    const int*   x_tok = (const int*)  d_in[0];
    const float* emb   = (const float*)d_in[2];
    const float* Wq    = (const float*)d_in[3];
    const float* bq    = (const float*)d_in[4];
    const float* Wk    = (const float*)d_in[5];
    const float* bk    = (const float*)d_in[6];
    const float* Wv    = (const float*)d_in[7];
    const float* bv    = (const float*)d_in[8];
    const float* Wo    = (const float*)d_in[9];
    const float* bo    = (const float*)d_in[10];
    const float* gma   = (const float*)d_in[11];
    const float* bta   = (const float*)d_in[12];
    const float* W1    = (const float*)d_in[13];
    const float* b1    = (const float*)d_in[14];
    const float* W2    = (const float*)d_in[15];
    const float* b2    = (const float*)d_in[16];
    const float* Wout  = (const float*)d_in[17];
    const float* bout  = (const float*)d_in[18];

    char* ws = (char*)d_ws;
    size_t off = 0;
    auto take = [&](size_t bytes) { char* p = ws + off; off += (bytes + 255) & ~(size_t)255; return p; };
    f16_t* wT    = (f16_t*)take(18874368ULL * 2);  // transposed f16 weights
    f16_t* hb    = (f16_t*)take(2097152ULL * 2);   // residual stream (f16)
    f16_t* qkv   = (f16_t*)take(6291456ULL * 2);   // [4096][1536] (Q,K used)
    f16_t* Vt    = (f16_t*)take(2097152ULL * 2);   // [64][64][512]
    f16_t* ao    = (f16_t*)take(2097152ULL * 2);   // attn out [4096][512]
    f16_t* f1    = (f16_t*)take(8388608ULL * 2);   // ffn hidden [4096][2048]
    f16_t* t16   = (f16_t*)take(4ULL * 2097152ULL * 2); // split-K f16 partials
    float* qkvb  = (float*)take(9216ULL * 4);
    float* parts = (float*)take(2560ULL * 4);

    setup_kernel<<<dim3(8740), 256, 0, stream>>>(Wq, Wk, Wv, Wo, W1, W2, wT,
                                                 x_tok, emb, hb, bq, bk, bv, qkvb);

    for (int l = 0; l < 6; ++l) {
        const f16_t* wl = wT + (long long)l * LSTR;
        // QKV: [4096,512]@[512,1536]; V heads written transposed to Vt
        gemm_kernel<64,128,64,2,2,1,0,1><<<dim3(64,12,1),256,0,stream>>>(hb, wl, qkvb + l*1536,
            qkv, Vt, 4096,1536,512, 512,512,1536, 1, 0,0,0,0,0,0);
        // flash attention v3: softmax(QK^T)V -> ao
        attn_flash_kernel<<<dim3(8,64),256,0,stream>>>(qkv, Vt, ao);
        // O proj: 64x128 split-K x2 (512 blocks) -> t16 slices
        gemm_kernel<64,128,64,2,2,1,0,0><<<dim3(64,4,2),256,0,stream>>>(ao, wl + 786432, nullptr,
            t16, nullptr, 4096,512,256, 512,512,512, 1, 256LL,0LL, 256LL,0LL, 2097152LL,0LL);
        add_ln_kernel<<<dim3(1024),256,0,stream>>>(t16, 2, 2097152LL, bo + l*512,
            gma + l*512, bta + l*512, hb);
        // FFN1 + relu -> f1 f16: 128x128/BK=64 (512 blocks, 8 K-steps)
        gemm_kernel<128,128,64,2,2,1,1,0><<<dim3(32,16,1),256,0,stream>>>(hb, wl + 1048576, b1 + l*2048,
            f1, nullptr, 4096,2048,512, 512,512,2048, 1, 0,0,0,0,0,0);
        // FFN2: 128x128/BK=64 split-K x4 (512 blocks, 8 K-steps) -> t16 slices
        gemm_kernel<128,128,64,2,2,1,0,0><<<dim3(32,4,4),256,0,stream>>>(f1, wl + 2097152, nullptr,
            t16, nullptr, 4096,512,512, 2048,2048,512, 1, 512LL,0LL, 512LL,0LL, 2097152LL,0LL);
        add_ln_kernel<<<dim3(1024),256,0,stream>>>(t16, 4, 2097152LL, b2 + l*512,
            gma + l*512, bta + l*512, hb);
    }

    head_partial_kernel<<<dim3(512),256,0,stream>>>(hb, Wout, parts);
    head_final_kernel  <<<dim3(1),64,0,stream>>>(parts, bout, (float*)d_out);
}